// Round 1
// baseline (1519.591 us; speedup 1.0000x reference)
//
#include <hip/hip_runtime.h>
#include <math.h>

#define NA_N 50000
#define NB_N 50000
#define DIN_N 128
#define HID_N 256
#define NE_N 1000000

static __device__ __forceinline__ float lrelu(float x) {
    return x >= 0.0f ? x : 0.01f * x;
}

// ---------------- CSR build: histogram -> scan -> scatter ----------------

__global__ void hist_kernel(const int* __restrict__ dst, int E, int* __restrict__ cnt) {
    int i = blockIdx.x * blockDim.x + threadIdx.x;
    if (i < E) atomicAdd(&cnt[dst[i]], 1);
}

// per-256-chunk sums
__global__ void scan_partial(const int* __restrict__ cnt, int n, int* __restrict__ bsum) {
    int tid = threadIdx.x;
    int i = blockIdx.x * 256 + tid;
    int s = (i < n) ? cnt[i] : 0;
    #pragma unroll
    for (int m = 1; m < 64; m <<= 1) s += __shfl_xor(s, m, 64);
    __shared__ int ws[4];
    if ((tid & 63) == 0) ws[tid >> 6] = s;
    __syncthreads();
    if (tid == 0) bsum[blockIdx.x] = ws[0] + ws[1] + ws[2] + ws[3];
}

// single block, exclusive scan of up to 256 chunk sums
__global__ void scan_block(const int* __restrict__ bsum, int nb, int* __restrict__ boff) {
    int tid = threadIdx.x;
    int v = (tid < nb) ? bsum[tid] : 0;
    int incl = v;
    #pragma unroll
    for (int m = 1; m < 64; m <<= 1) {
        int o = __shfl_up(incl, m, 64);
        if ((tid & 63) >= m) incl += o;
    }
    __shared__ int wt[4];
    if ((tid & 63) == 63) wt[tid >> 6] = incl;
    __syncthreads();
    int add = 0;
    for (int w0 = 0; w0 < (tid >> 6); ++w0) add += wt[w0];
    incl += add;
    if (tid < nb) boff[tid] = incl - v;   // exclusive
}

__global__ void scan_final(const int* __restrict__ cnt, int n, const int* __restrict__ boff,
                           int* __restrict__ offs) {
    int tid = threadIdx.x;
    int i = blockIdx.x * 256 + tid;
    int v = (i < n) ? cnt[i] : 0;
    int incl = v;
    #pragma unroll
    for (int m = 1; m < 64; m <<= 1) {
        int o = __shfl_up(incl, m, 64);
        if ((tid & 63) >= m) incl += o;
    }
    __shared__ int wt[4];
    if ((tid & 63) == 63) wt[tid >> 6] = incl;
    __syncthreads();
    int add = 0;
    for (int w0 = 0; w0 < (tid >> 6); ++w0) add += wt[w0];
    incl += add;
    if (i < n) offs[i + 1] = boff[blockIdx.x] + incl;
    if (i == 0) offs[0] = 0;
}

__global__ void scatter_kernel(const int* __restrict__ src, const int* __restrict__ dst, int E,
                               const int* __restrict__ offs, int* __restrict__ cur,
                               int* __restrict__ ssrc) {
    int i = blockIdx.x * blockDim.x + threadIdx.x;
    if (i < E) {
        int d = dst[i];
        int p = atomicAdd(&cur[d], 1);
        ssrc[offs[d] + p] = src[i];
    }
}

// ---------------- aggregation: one wave per destination node ----------------

template <int D>
__global__ __launch_bounds__(256)
void agg_mean(const float* __restrict__ xsrc, const int* __restrict__ ssrc,
              const int* __restrict__ offs, float* __restrict__ mean, int n) {
    int w = blockIdx.x * 4 + (threadIdx.x >> 6);
    int lane = threadIdx.x & 63;
    if (w >= n) return;
    int beg = offs[w], end = offs[w + 1];
    constexpr int C = D / 64;
    float acc[C];
    #pragma unroll
    for (int c = 0; c < C; ++c) acc[c] = 0.0f;
    for (int e = beg; e < end; ++e) {
        int s = ssrc[e];
        const float* p = xsrc + (size_t)s * D + lane * C;
        if constexpr (C == 2) {
            float2 v = *(const float2*)p;
            acc[0] += v.x; acc[1] += v.y;
        } else {
            float4 v = *(const float4*)p;
            acc[0] += v.x; acc[1] += v.y; acc[2] += v.z; acc[3] += v.w;
        }
    }
    float inv = 1.0f / fmaxf((float)(end - beg), 1.0f);
    float* q = mean + (size_t)w * D + lane * C;
    if constexpr (C == 2) {
        float2 v; v.x = acc[0] * inv; v.y = acc[1] * inv;
        *(float2*)q = v;
    } else {
        float4 v; v.x = acc[0] * inv; v.y = acc[1] * inv; v.z = acc[2] * inv; v.w = acc[3] * inv;
        *(float4*)q = v;
    }
}

// ------- fused dual-GEMM + bias + L2-normalize + leaky_relu epilogue -------
// out[n,256] = lrelu(normalize(A@Wl + bias + X@Wr)) ; safe for X == out (in-place):
// each block reads only its own 64 rows of X before writing them.

template <int D>
__global__ __launch_bounds__(256)
void gemm_norm_lrelu(const float* __restrict__ A, const float* __restrict__ X,
                     const float* __restrict__ Wl, const float* __restrict__ Wr,
                     const float* __restrict__ bias, float* __restrict__ out, int n) {
    constexpr int BM = 64, BN = 256, BK = 32;
    __shared__ __align__(16) float As[BK][BM + 4];   // transposed A tile, pitch 68 (16B-aligned rows)
    __shared__ __align__(16) float Ws[BK][BN];       // W tile (32x256), 32KB

    const int tid = threadIdx.x;
    const int tx = tid & 15;       // 16 col-groups
    const int ty = tid >> 4;       // 16 row-groups (4 rows each)
    const int row0 = blockIdx.x * BM;

    float acc[4][4][4];            // [row i][col group j at tx*4+64j][c]
    #pragma unroll
    for (int i = 0; i < 4; ++i)
        #pragma unroll
        for (int j = 0; j < 4; ++j)
            #pragma unroll
            for (int c = 0; c < 4; ++c) acc[i][j][c] = 0.0f;

    #pragma unroll
    for (int pass = 0; pass < 2; ++pass) {
        const float* __restrict__ M = pass ? X : A;
        const float* __restrict__ W = pass ? Wr : Wl;
        for (int k0 = 0; k0 < D; k0 += BK) {
            __syncthreads();
            // A tile: 64 rows x 32 k, stored transposed As[k][row]
            #pragma unroll
            for (int q = 0; q < 2; ++q) {
                int idx = tid + q * 256;         // 0..511 float4s
                int r = idx >> 3;                // row in tile
                int kk = (idx & 7) << 2;         // k within tile
                float4 v = make_float4(0.f, 0.f, 0.f, 0.f);
                if (row0 + r < n)
                    v = *(const float4*)(M + (size_t)(row0 + r) * D + k0 + kk);
                As[kk + 0][r] = v.x;
                As[kk + 1][r] = v.y;
                As[kk + 2][r] = v.z;
                As[kk + 3][r] = v.w;
            }
            // W tile: 32 x 256 contiguous copy
            #pragma unroll
            for (int q = 0; q < 8; ++q) {
                int idx = tid + q * 256;         // 0..2047 float4s
                *((float4*)&Ws[0][0] + idx) = *((const float4*)(W + (size_t)k0 * BN) + idx);
            }
            __syncthreads();
            #pragma unroll
            for (int kk = 0; kk < BK; ++kk) {
                float a[4];
                *(float4*)a = *(const float4*)&As[kk][ty * 4];
                float wv[4][4];
                #pragma unroll
                for (int j = 0; j < 4; ++j)
                    *(float4*)wv[j] = *(const float4*)&Ws[kk][tx * 4 + 64 * j];
                #pragma unroll
                for (int i = 0; i < 4; ++i)
                    #pragma unroll
                    for (int j = 0; j < 4; ++j)
                        #pragma unroll
                        for (int c = 0; c < 4; ++c)
                            acc[i][j][c] = fmaf(a[i], wv[j][c], acc[i][j][c]);
            }
        }
    }

    float bv[4][4];
    #pragma unroll
    for (int j = 0; j < 4; ++j)
        *(float4*)bv[j] = *(const float4*)(bias + tx * 4 + 64 * j);

    #pragma unroll
    for (int i = 0; i < 4; ++i) {
        int row = row0 + ty * 4 + i;
        float ss = 0.0f;
        #pragma unroll
        for (int j = 0; j < 4; ++j)
            #pragma unroll
            for (int c = 0; c < 4; ++c) {
                acc[i][j][c] += bv[j][c];
                ss = fmaf(acc[i][j][c], acc[i][j][c], ss);
            }
        // reduce across the 16 tx lanes that share this row
        #pragma unroll
        for (int m = 1; m < 16; m <<= 1) ss += __shfl_xor(ss, m, 64);
        float inv = 1.0f / fmaxf(sqrtf(ss), 1e-12f);
        if (row < n) {
            #pragma unroll
            for (int j = 0; j < 4; ++j) {
                float o[4];
                #pragma unroll
                for (int c = 0; c < 4; ++c) o[c] = lrelu(acc[i][j][c] * inv);
                *(float4*)(out + (size_t)row * HID_N + tx * 4 + 64 * j) = *(float4*)o;
            }
        }
    }
}

// ---------------- launcher ----------------

extern "C" void kernel_launch(void* const* d_in, const int* in_sizes, int n_in,
                              void* d_out, int out_size, void* d_ws, size_t ws_size,
                              hipStream_t stream) {
    const float* xa = (const float*)d_in[0];
    const float* xb = (const float*)d_in[1];
    const int* ei_ab = (const int*)d_in[2];   // row0 = src(a), row1 = dst(b)
    const int* ei_ba = (const int*)d_in[3];   // row0 = src(b), row1 = dst(a)
    const float* Wl0_ab = (const float*)d_in[4];
    const float* Wr0_ab = (const float*)d_in[5];
    const float* b0_ab = (const float*)d_in[6];
    const float* Wl0_ba = (const float*)d_in[7];
    const float* Wr0_ba = (const float*)d_in[8];
    const float* b0_ba = (const float*)d_in[9];
    const float* Wl1_ab = (const float*)d_in[10];
    const float* Wr1_ab = (const float*)d_in[11];
    const float* b1_ab = (const float*)d_in[12];
    const float* Wl1_ba = (const float*)d_in[13];
    const float* Wr1_ba = (const float*)d_in[14];
    const float* b1_ba = (const float*)d_in[15];

    float* out_a = (float*)d_out;                       // final xa  [NA,256] (also h_a)
    float* out_b = out_a + (size_t)NA_N * HID_N;        // final xb  [NB,256] (also h_b)

    char* w = (char*)d_ws;
    auto carve = [&](size_t bytes) -> char* {
        char* p = w;
        w += (bytes + 255) & ~(size_t)255;
        return p;
    };
    float* agg1 = (float*)carve((size_t)NB_N * HID_N * 4);   // mean for dst=b
    float* agg2 = (float*)carve((size_t)NA_N * HID_N * 4);   // mean for dst=a
    int* cnt_b = (int*)carve((size_t)NB_N * 4);
    int* cnt_a = (int*)carve((size_t)NA_N * 4);
    int* off_b = (int*)carve((size_t)(NB_N + 1) * 4);
    int* off_a = (int*)carve((size_t)(NA_N + 1) * 4);
    int* cur_b = (int*)carve((size_t)NB_N * 4);
    int* cur_a = (int*)carve((size_t)NA_N * 4);
    int* bsum = (int*)carve(256 * 4);
    int* boff = (int*)carve(256 * 4);
    int* ssrc_ab = (int*)carve((size_t)NE_N * 4);
    int* ssrc_ba = (int*)carve((size_t)NE_N * 4);

    hipMemsetAsync(cnt_b, 0, NB_N * 4, stream);
    hipMemsetAsync(cnt_a, 0, NA_N * 4, stream);
    hipMemsetAsync(cur_b, 0, NB_N * 4, stream);
    hipMemsetAsync(cur_a, 0, NA_N * 4, stream);

    const int eb = (NE_N + 255) / 256;
    hist_kernel<<<eb, 256, 0, stream>>>(ei_ab + NE_N, NE_N, cnt_b);
    hist_kernel<<<eb, 256, 0, stream>>>(ei_ba + NE_N, NE_N, cnt_a);

    const int nchunk_b = (NB_N + 255) / 256;
    scan_partial<<<nchunk_b, 256, 0, stream>>>(cnt_b, NB_N, bsum);
    scan_block<<<1, 256, 0, stream>>>(bsum, nchunk_b, boff);
    scan_final<<<nchunk_b, 256, 0, stream>>>(cnt_b, NB_N, boff, off_b);

    const int nchunk_a = (NA_N + 255) / 256;
    scan_partial<<<nchunk_a, 256, 0, stream>>>(cnt_a, NA_N, bsum);
    scan_block<<<1, 256, 0, stream>>>(bsum, nchunk_a, boff);
    scan_final<<<nchunk_a, 256, 0, stream>>>(cnt_a, NA_N, boff, off_a);

    scatter_kernel<<<eb, 256, 0, stream>>>(ei_ab, ei_ab + NE_N, NE_N, off_b, cur_b, ssrc_ab);
    scatter_kernel<<<eb, 256, 0, stream>>>(ei_ba, ei_ba + NE_N, NE_N, off_a, cur_a, ssrc_ba);

    // ---- layer 0 (D = 128) ----
    agg_mean<DIN_N><<<(NB_N + 3) / 4, 256, 0, stream>>>(xa, ssrc_ab, off_b, agg1, NB_N);
    gemm_norm_lrelu<DIN_N><<<(NB_N + 63) / 64, 256, 0, stream>>>(agg1, xb, Wl0_ab, Wr0_ab, b0_ab, out_b, NB_N);
    agg_mean<DIN_N><<<(NA_N + 3) / 4, 256, 0, stream>>>(xb, ssrc_ba, off_a, agg2, NA_N);
    gemm_norm_lrelu<DIN_N><<<(NA_N + 63) / 64, 256, 0, stream>>>(agg2, xa, Wl0_ba, Wr0_ba, b0_ba, out_a, NA_N);

    // ---- layer 1 (D = 256) ---- (both aggs BEFORE the in-place GEMMs)
    agg_mean<HID_N><<<(NB_N + 3) / 4, 256, 0, stream>>>(out_a, ssrc_ab, off_b, agg1, NB_N);
    agg_mean<HID_N><<<(NA_N + 3) / 4, 256, 0, stream>>>(out_b, ssrc_ba, off_a, agg2, NA_N);
    gemm_norm_lrelu<HID_N><<<(NB_N + 63) / 64, 256, 0, stream>>>(agg1, out_b, Wl1_ab, Wr1_ab, b1_ab, out_b, NB_N);
    gemm_norm_lrelu<HID_N><<<(NA_N + 63) / 64, 256, 0, stream>>>(agg2, out_a, Wl1_ba, Wr1_ba, b1_ba, out_a, NA_N);
}

// Round 2
// 912.526 us; speedup vs baseline: 1.6653x; 1.6653x over previous
//
#include <hip/hip_runtime.h>
#include <hip/hip_bf16.h>
#include <math.h>
#include <string.h>

#define NA_N 50000
#define NB_N 50000
#define DIN_N 128
#define HID_N 256
#define NE_N 1000000

typedef short short8 __attribute__((ext_vector_type(8)));
typedef float f32x4 __attribute__((ext_vector_type(4)));

static __device__ __forceinline__ float lrelu(float x) {
    return x >= 0.0f ? x : 0.01f * x;
}

static __device__ __forceinline__ unsigned short f2bf(float f) {
    __hip_bfloat16 h = __float2bfloat16(f);   // RNE
    unsigned short u;
    memcpy(&u, &h, 2);
    return u;
}

// ---------------- CSR build: histogram -> scan -> scatter ----------------

__global__ void hist_kernel(const int* __restrict__ dst, int E, int* __restrict__ cnt) {
    int i = blockIdx.x * blockDim.x + threadIdx.x;
    if (i < E) atomicAdd(&cnt[dst[i]], 1);
}

__global__ void scan_partial(const int* __restrict__ cnt, int n, int* __restrict__ bsum) {
    int tid = threadIdx.x;
    int i = blockIdx.x * 256 + tid;
    int s = (i < n) ? cnt[i] : 0;
    #pragma unroll
    for (int m = 1; m < 64; m <<= 1) s += __shfl_xor(s, m, 64);
    __shared__ int ws[4];
    if ((tid & 63) == 0) ws[tid >> 6] = s;
    __syncthreads();
    if (tid == 0) bsum[blockIdx.x] = ws[0] + ws[1] + ws[2] + ws[3];
}

__global__ void scan_block(const int* __restrict__ bsum, int nb, int* __restrict__ boff) {
    int tid = threadIdx.x;
    int v = (tid < nb) ? bsum[tid] : 0;
    int incl = v;
    #pragma unroll
    for (int m = 1; m < 64; m <<= 1) {
        int o = __shfl_up(incl, m, 64);
        if ((tid & 63) >= m) incl += o;
    }
    __shared__ int wt[4];
    if ((tid & 63) == 63) wt[tid >> 6] = incl;
    __syncthreads();
    int add = 0;
    for (int w0 = 0; w0 < (tid >> 6); ++w0) add += wt[w0];
    incl += add;
    if (tid < nb) boff[tid] = incl - v;   // exclusive
}

__global__ void scan_final(const int* __restrict__ cnt, int n, const int* __restrict__ boff,
                           int* __restrict__ offs) {
    int tid = threadIdx.x;
    int i = blockIdx.x * 256 + tid;
    int v = (i < n) ? cnt[i] : 0;
    int incl = v;
    #pragma unroll
    for (int m = 1; m < 64; m <<= 1) {
        int o = __shfl_up(incl, m, 64);
        if ((tid & 63) >= m) incl += o;
    }
    __shared__ int wt[4];
    if ((tid & 63) == 63) wt[tid >> 6] = incl;
    __syncthreads();
    int add = 0;
    for (int w0 = 0; w0 < (tid >> 6); ++w0) add += wt[w0];
    incl += add;
    if (i < n) offs[i + 1] = boff[blockIdx.x] + incl;
    if (i == 0) offs[0] = 0;
}

__global__ void scatter_kernel(const int* __restrict__ src, const int* __restrict__ dst, int E,
                               const int* __restrict__ offs, int* __restrict__ cur,
                               int* __restrict__ ssrc) {
    int i = blockIdx.x * blockDim.x + threadIdx.x;
    if (i < E) {
        int d = dst[i];
        int p = atomicAdd(&cur[d], 1);
        ssrc[offs[d] + p] = src[i];
    }
}

// ---------------- aggregation: one wave per destination node ----------------

template <int D>
__global__ __launch_bounds__(256)
void agg_mean(const float* __restrict__ xsrc, const int* __restrict__ ssrc,
              const int* __restrict__ offs, float* __restrict__ mean, int n) {
    int w = blockIdx.x * 4 + (threadIdx.x >> 6);
    int lane = threadIdx.x & 63;
    if (w >= n) return;
    int beg = offs[w], end = offs[w + 1];
    constexpr int C = D / 64;
    float acc[C];
    #pragma unroll
    for (int c = 0; c < C; ++c) acc[c] = 0.0f;
    for (int e = beg; e < end; ++e) {
        int s = ssrc[e];
        const float* p = xsrc + (size_t)s * D + lane * C;
        if constexpr (C == 2) {
            float2 v = *(const float2*)p;
            acc[0] += v.x; acc[1] += v.y;
        } else {
            float4 v = *(const float4*)p;
            acc[0] += v.x; acc[1] += v.y; acc[2] += v.z; acc[3] += v.w;
        }
    }
    float inv = 1.0f / fmaxf((float)(end - beg), 1.0f);
    float* q = mean + (size_t)w * D + lane * C;
    if constexpr (C == 2) {
        float2 v; v.x = acc[0] * inv; v.y = acc[1] * inv;
        *(float2*)q = v;
    } else {
        float4 v; v.x = acc[0] * inv; v.y = acc[1] * inv; v.z = acc[2] * inv; v.w = acc[3] * inv;
        *(float4*)q = v;
    }
}

// ---------------- one-time weight transpose + bf16 convert ----------------
// W[k][c] f32  ->  Wt[c][k] bf16   (c = 0..255, k = 0..D-1)

__global__ void transpose_w(const float* __restrict__ W, unsigned short* __restrict__ Wt, int D) {
    int wg = blockIdx.x * 4 + (threadIdx.x >> 6);
    int lane = threadIdx.x & 63;
    int kchunks = D >> 6;
    int c = wg / kchunks;
    int kc = wg - c * kchunks;
    int k = kc * 64 + lane;
    if (c < 256) Wt[(size_t)c * D + k] = f2bf(W[(size_t)k * 256 + c]);
}

// ------- fused MFMA dual-GEMM + bias + L2-normalize + leaky_relu -------
// out[n,256] = lrelu(normalize(A@Wl + bias + X@Wr)) ; in-place-safe for X == out
// (each block reads only its own 64 rows of X, all before the epilogue writes them).
// Wtl/Wtr are bf16, transposed [col][k]. A/X fp32 converted to bf16 during staging.

template <int D>
__global__ __launch_bounds__(256)
void mfma_gemm_norm_lrelu(const float* __restrict__ A, const float* __restrict__ X,
                          const unsigned short* __restrict__ Wtl,
                          const unsigned short* __restrict__ Wtr,
                          const float* __restrict__ bias, float* __restrict__ out, int n) {
    constexpr int BM = 64, BK = 32;
    constexpr int PITCH = 40;   // ushorts per LDS row (80 B): 2-way bank aliasing only
    __shared__ __align__(16) unsigned short Asl[BM * PITCH];     //  5 KB
    __shared__ __align__(16) unsigned short Wsl[256 * PITCH];    // 20 KB
    __shared__ float red[4][BM];
    __shared__ float invn[BM];

    const int tid = threadIdx.x;
    const int wid = tid >> 6;      // 4 waves, each owns 64-col block
    const int lane = tid & 63;
    const int cl = lane & 15;
    const int g = lane >> 4;
    const int row0 = blockIdx.x * BM;

    f32x4 acc[4][4];               // [m: 16-row frag][nn: 16-col frag]
    #pragma unroll
    for (int m = 0; m < 4; ++m)
        #pragma unroll
        for (int nn = 0; nn < 4; ++nn)
            acc[m][nn] = (f32x4){0.f, 0.f, 0.f, 0.f};

    #pragma unroll
    for (int pass = 0; pass < 2; ++pass) {
        const float* __restrict__ M = pass ? X : A;
        const unsigned short* __restrict__ Wt = pass ? Wtr : Wtl;
        for (int k0 = 0; k0 < D; k0 += BK) {
            __syncthreads();
            // stage A: 64 rows x 32 k, fp32 -> bf16
            #pragma unroll
            for (int q = 0; q < 2; ++q) {
                int idx = tid + q * 256;          // 0..511 float4 units
                int r = idx >> 3;
                int k4 = (idx & 7) << 2;
                float4 v = make_float4(0.f, 0.f, 0.f, 0.f);
                if (row0 + r < n) v = *(const float4*)(M + (size_t)(row0 + r) * D + k0 + k4);
                ushort4 b4;
                b4.x = f2bf(v.x); b4.y = f2bf(v.y); b4.z = f2bf(v.z); b4.w = f2bf(v.w);
                *(ushort4*)(&Asl[r * PITCH + k4]) = b4;
            }
            // stage W: 256 cols x 32 k, bf16 copy from Wt[c][k]
            #pragma unroll
            for (int q = 0; q < 4; ++q) {
                int idx = tid + q * 256;          // 0..1023 16B units
                int c = idx >> 2;
                int kq = (idx & 3) << 3;          // ushort offset 0,8,16,24
                *(float4*)(&Wsl[c * PITCH + kq]) =
                    *(const float4*)(Wt + (size_t)c * D + k0 + kq);
            }
            __syncthreads();
            short8 af[4], bfr[4];
            const int g8 = g * 8;
            #pragma unroll
            for (int m = 0; m < 4; ++m)
                af[m] = *(const short8*)(&Asl[(m * 16 + cl) * PITCH + g8]);
            #pragma unroll
            for (int nn = 0; nn < 4; ++nn)
                bfr[nn] = *(const short8*)(&Wsl[(wid * 64 + nn * 16 + cl) * PITCH + g8]);
            #pragma unroll
            for (int m = 0; m < 4; ++m)
                #pragma unroll
                for (int nn = 0; nn < 4; ++nn)
                    acc[m][nn] = __builtin_amdgcn_mfma_f32_16x16x32_bf16(
                        af[m], bfr[nn], acc[m][nn], 0, 0, 0);
        }
    }

    // ---- epilogue: bias, row L2-norm, leaky-relu ----
    float bv[4];
    #pragma unroll
    for (int nn = 0; nn < 4; ++nn) bv[nn] = bias[wid * 64 + nn * 16 + cl];

    float ss[4][4];   // [m][reg] partial sum-of-squares over this wave's 64 cols
    #pragma unroll
    for (int m = 0; m < 4; ++m)
        #pragma unroll
        for (int r = 0; r < 4; ++r) {
            float s = 0.f;
            #pragma unroll
            for (int nn = 0; nn < 4; ++nn) {
                acc[m][nn][r] += bv[nn];
                s = fmaf(acc[m][nn][r], acc[m][nn][r], s);
            }
            ss[m][r] = s;
        }
    #pragma unroll
    for (int mask = 1; mask < 16; mask <<= 1)
        #pragma unroll
        for (int m = 0; m < 4; ++m)
            #pragma unroll
            for (int r = 0; r < 4; ++r)
                ss[m][r] += __shfl_xor(ss[m][r], mask, 64);
    if (cl == 0) {
        #pragma unroll
        for (int m = 0; m < 4; ++m)
            #pragma unroll
            for (int r = 0; r < 4; ++r)
                red[wid][m * 16 + g * 4 + r] = ss[m][r];
    }
    __syncthreads();
    if (tid < BM) {
        float tot = red[0][tid] + red[1][tid] + red[2][tid] + red[3][tid];
        invn[tid] = 1.0f / fmaxf(sqrtf(tot), 1e-12f);
    }
    __syncthreads();
    #pragma unroll
    for (int m = 0; m < 4; ++m)
        #pragma unroll
        for (int r = 0; r < 4; ++r) {
            int row = m * 16 + g * 4 + r;
            if (row0 + row < n) {
                float iv = invn[row];
                #pragma unroll
                for (int nn = 0; nn < 4; ++nn)
                    out[(size_t)(row0 + row) * HID_N + wid * 64 + nn * 16 + cl] =
                        lrelu(acc[m][nn][r] * iv);
            }
        }
}

// ---------------- launcher ----------------

extern "C" void kernel_launch(void* const* d_in, const int* in_sizes, int n_in,
                              void* d_out, int out_size, void* d_ws, size_t ws_size,
                              hipStream_t stream) {
    const float* xa = (const float*)d_in[0];
    const float* xb = (const float*)d_in[1];
    const int* ei_ab = (const int*)d_in[2];
    const int* ei_ba = (const int*)d_in[3];
    const float* Wl0_ab = (const float*)d_in[4];
    const float* Wr0_ab = (const float*)d_in[5];
    const float* b0_ab = (const float*)d_in[6];
    const float* Wl0_ba = (const float*)d_in[7];
    const float* Wr0_ba = (const float*)d_in[8];
    const float* b0_ba = (const float*)d_in[9];
    const float* Wl1_ab = (const float*)d_in[10];
    const float* Wr1_ab = (const float*)d_in[11];
    const float* b1_ab = (const float*)d_in[12];
    const float* Wl1_ba = (const float*)d_in[13];
    const float* Wr1_ba = (const float*)d_in[14];
    const float* b1_ba = (const float*)d_in[15];

    float* out_a = (float*)d_out;
    float* out_b = out_a + (size_t)NA_N * HID_N;

    char* w = (char*)d_ws;
    auto carve = [&](size_t bytes) -> char* {
        char* p = w;
        w += (bytes + 255) & ~(size_t)255;
        return p;
    };
    float* agg1 = (float*)carve((size_t)NB_N * HID_N * 4);
    float* agg2 = (float*)carve((size_t)NA_N * HID_N * 4);
    int* cnt_b = (int*)carve((size_t)NB_N * 4);
    int* cnt_a = (int*)carve((size_t)NA_N * 4);
    int* off_b = (int*)carve((size_t)(NB_N + 1) * 4);
    int* off_a = (int*)carve((size_t)(NA_N + 1) * 4);
    int* cur_b = (int*)carve((size_t)NB_N * 4);
    int* cur_a = (int*)carve((size_t)NA_N * 4);
    int* bsum = (int*)carve(256 * 4);
    int* boff = (int*)carve(256 * 4);
    int* ssrc_ab = (int*)carve((size_t)NE_N * 4);
    int* ssrc_ba = (int*)carve((size_t)NE_N * 4);
    unsigned short* wt_l0ab = (unsigned short*)carve((size_t)DIN_N * 256 * 2);
    unsigned short* wt_r0ab = (unsigned short*)carve((size_t)DIN_N * 256 * 2);
    unsigned short* wt_l0ba = (unsigned short*)carve((size_t)DIN_N * 256 * 2);
    unsigned short* wt_r0ba = (unsigned short*)carve((size_t)DIN_N * 256 * 2);
    unsigned short* wt_l1ab = (unsigned short*)carve((size_t)HID_N * 256 * 2);
    unsigned short* wt_r1ab = (unsigned short*)carve((size_t)HID_N * 256 * 2);
    unsigned short* wt_l1ba = (unsigned short*)carve((size_t)HID_N * 256 * 2);
    unsigned short* wt_r1ba = (unsigned short*)carve((size_t)HID_N * 256 * 2);

    hipMemsetAsync(cnt_b, 0, NB_N * 4, stream);
    hipMemsetAsync(cnt_a, 0, NA_N * 4, stream);
    hipMemsetAsync(cur_b, 0, NB_N * 4, stream);
    hipMemsetAsync(cur_a, 0, NA_N * 4, stream);

    // one-time weight transposes (bf16)
    transpose_w<<<128, 256, 0, stream>>>(Wl0_ab, wt_l0ab, DIN_N);
    transpose_w<<<128, 256, 0, stream>>>(Wr0_ab, wt_r0ab, DIN_N);
    transpose_w<<<128, 256, 0, stream>>>(Wl0_ba, wt_l0ba, DIN_N);
    transpose_w<<<128, 256, 0, stream>>>(Wr0_ba, wt_r0ba, DIN_N);
    transpose_w<<<256, 256, 0, stream>>>(Wl1_ab, wt_l1ab, HID_N);
    transpose_w<<<256, 256, 0, stream>>>(Wr1_ab, wt_r1ab, HID_N);
    transpose_w<<<256, 256, 0, stream>>>(Wl1_ba, wt_l1ba, HID_N);
    transpose_w<<<256, 256, 0, stream>>>(Wr1_ba, wt_r1ba, HID_N);

    const int eb = (NE_N + 255) / 256;
    hist_kernel<<<eb, 256, 0, stream>>>(ei_ab + NE_N, NE_N, cnt_b);
    hist_kernel<<<eb, 256, 0, stream>>>(ei_ba + NE_N, NE_N, cnt_a);

    const int nchunk_b = (NB_N + 255) / 256;
    scan_partial<<<nchunk_b, 256, 0, stream>>>(cnt_b, NB_N, bsum);
    scan_block<<<1, 256, 0, stream>>>(bsum, nchunk_b, boff);
    scan_final<<<nchunk_b, 256, 0, stream>>>(cnt_b, NB_N, boff, off_b);

    const int nchunk_a = (NA_N + 255) / 256;
    scan_partial<<<nchunk_a, 256, 0, stream>>>(cnt_a, NA_N, bsum);
    scan_block<<<1, 256, 0, stream>>>(bsum, nchunk_a, boff);
    scan_final<<<nchunk_a, 256, 0, stream>>>(cnt_a, NA_N, boff, off_a);

    scatter_kernel<<<eb, 256, 0, stream>>>(ei_ab, ei_ab + NE_N, NE_N, off_b, cur_b, ssrc_ab);
    scatter_kernel<<<eb, 256, 0, stream>>>(ei_ba, ei_ba + NE_N, NE_N, off_a, cur_a, ssrc_ba);

    const int gb = (NB_N + 63) / 64;
    const int ga = (NA_N + 63) / 64;

    // ---- layer 0 (D = 128) ----
    agg_mean<DIN_N><<<(NB_N + 3) / 4, 256, 0, stream>>>(xa, ssrc_ab, off_b, agg1, NB_N);
    mfma_gemm_norm_lrelu<DIN_N><<<gb, 256, 0, stream>>>(agg1, xb, wt_l0ab, wt_r0ab, b0_ab, out_b, NB_N);
    agg_mean<DIN_N><<<(NA_N + 3) / 4, 256, 0, stream>>>(xb, ssrc_ba, off_a, agg2, NA_N);
    mfma_gemm_norm_lrelu<DIN_N><<<ga, 256, 0, stream>>>(agg2, xa, wt_l0ba, wt_r0ba, b0_ba, out_a, NA_N);

    // ---- layer 1 (D = 256) ---- (both aggs BEFORE the in-place GEMMs)
    agg_mean<HID_N><<<(NB_N + 3) / 4, 256, 0, stream>>>(out_a, ssrc_ab, off_b, agg1, NB_N);
    agg_mean<HID_N><<<(NA_N + 3) / 4, 256, 0, stream>>>(out_b, ssrc_ba, off_a, agg2, NA_N);
    mfma_gemm_norm_lrelu<HID_N><<<gb, 256, 0, stream>>>(agg1, out_b, wt_l1ab, wt_r1ab, b1_ab, out_b, NB_N);
    mfma_gemm_norm_lrelu<HID_N><<<ga, 256, 0, stream>>>(agg2, out_a, wt_l1ba, wt_r1ba, b1_ba, out_a, NA_N);
}

// Round 3
// 595.172 us; speedup vs baseline: 2.5532x; 1.5332x over previous
//
#include <hip/hip_runtime.h>
#include <hip/hip_bf16.h>
#include <math.h>
#include <string.h>

#define NA_N 50000
#define NB_N 50000
#define DIN_N 128
#define HID_N 256
#define NE_N 1000000

typedef short short8 __attribute__((ext_vector_type(8)));
typedef float f32x4 __attribute__((ext_vector_type(4)));

static __device__ __forceinline__ float lrelu(float x) {
    return x >= 0.0f ? x : 0.01f * x;
}

static __device__ __forceinline__ unsigned short f2bf(float f) {
    __hip_bfloat16 h = __float2bfloat16(f);   // RNE
    unsigned short u;
    memcpy(&u, &h, 2);
    return u;
}

static __device__ __forceinline__ float bf2f(unsigned short u) {
    unsigned int x = ((unsigned int)u) << 16;
    float f;
    memcpy(&f, &x, 4);
    return f;
}

// ---------------- fp32 -> bf16 array convert ----------------

__global__ void f2bf_arr(const float* __restrict__ in, unsigned short* __restrict__ out, int n4) {
    int i = blockIdx.x * blockDim.x + threadIdx.x;   // float4 units
    if (i < n4) {
        float4 v = ((const float4*)in)[i];
        ushort4 b;
        b.x = f2bf(v.x); b.y = f2bf(v.y); b.z = f2bf(v.z); b.w = f2bf(v.w);
        ((ushort4*)out)[i] = b;
    }
}

// ---------------- CSR build: histogram -> scan -> scatter ----------------

__global__ void hist_kernel(const int* __restrict__ dst, int E, int* __restrict__ cnt) {
    int i = blockIdx.x * blockDim.x + threadIdx.x;
    if (i < E) atomicAdd(&cnt[dst[i]], 1);
}

__global__ void scan_partial(const int* __restrict__ cnt, int n, int* __restrict__ bsum) {
    int tid = threadIdx.x;
    int i = blockIdx.x * 256 + tid;
    int s = (i < n) ? cnt[i] : 0;
    #pragma unroll
    for (int m = 1; m < 64; m <<= 1) s += __shfl_xor(s, m, 64);
    __shared__ int ws[4];
    if ((tid & 63) == 0) ws[tid >> 6] = s;
    __syncthreads();
    if (tid == 0) bsum[blockIdx.x] = ws[0] + ws[1] + ws[2] + ws[3];
}

__global__ void scan_block(const int* __restrict__ bsum, int nb, int* __restrict__ boff) {
    int tid = threadIdx.x;
    int v = (tid < nb) ? bsum[tid] : 0;
    int incl = v;
    #pragma unroll
    for (int m = 1; m < 64; m <<= 1) {
        int o = __shfl_up(incl, m, 64);
        if ((tid & 63) >= m) incl += o;
    }
    __shared__ int wt[4];
    if ((tid & 63) == 63) wt[tid >> 6] = incl;
    __syncthreads();
    int add = 0;
    for (int w0 = 0; w0 < (tid >> 6); ++w0) add += wt[w0];
    incl += add;
    if (tid < nb) boff[tid] = incl - v;   // exclusive
}

__global__ void scan_final(const int* __restrict__ cnt, int n, const int* __restrict__ boff,
                           int* __restrict__ offs) {
    int tid = threadIdx.x;
    int i = blockIdx.x * 256 + tid;
    int v = (i < n) ? cnt[i] : 0;
    int incl = v;
    #pragma unroll
    for (int m = 1; m < 64; m <<= 1) {
        int o = __shfl_up(incl, m, 64);
        if ((tid & 63) >= m) incl += o;
    }
    __shared__ int wt[4];
    if ((tid & 63) == 63) wt[tid >> 6] = incl;
    __syncthreads();
    int add = 0;
    for (int w0 = 0; w0 < (tid >> 6); ++w0) add += wt[w0];
    incl += add;
    if (i < n) offs[i + 1] = boff[blockIdx.x] + incl;
    if (i == 0) offs[0] = 0;
}

__global__ void scatter_kernel(const int* __restrict__ src, const int* __restrict__ dst, int E,
                               const int* __restrict__ offs, int* __restrict__ cur,
                               int* __restrict__ ssrc) {
    int i = blockIdx.x * blockDim.x + threadIdx.x;
    if (i < E) {
        int d = dst[i];
        int p = atomicAdd(&cur[d], 1);
        ssrc[offs[d] + p] = src[i];
    }
}

// -------- aggregation: one wave per destination, 4-deep gather pipeline --------
// bf16 source rows, fp32 accumulate, bf16 mean out.  C = ushorts per lane (D = 64*C).

template <int C>
__global__ __launch_bounds__(256)
void agg_mean_bf(const unsigned short* __restrict__ xsrc, const int* __restrict__ ssrc,
                 const int* __restrict__ offs, unsigned short* __restrict__ mean, int n) {
    constexpr int D = C * 64;
    int w = blockIdx.x * 4 + (threadIdx.x >> 6);
    int lane = threadIdx.x & 63;
    if (w >= n) return;
    int beg = offs[w], end = offs[w + 1];
    float acc[C];
    #pragma unroll
    for (int c = 0; c < C; ++c) acc[c] = 0.0f;

    for (int e = beg; e < end; e += 4) {
        int idx[4];
        float wt[4];
        #pragma unroll
        for (int u = 0; u < 4; ++u) {
            int ee = e + u;
            idx[u] = ssrc[ee < end ? ee : end - 1];
            wt[u] = (ee < end) ? 1.0f : 0.0f;
        }
        if constexpr (C == 2) {
            unsigned int v[4];
            #pragma unroll
            for (int u = 0; u < 4; ++u)
                v[u] = *(const unsigned int*)(xsrc + (size_t)idx[u] * D + lane * 2);
            #pragma unroll
            for (int u = 0; u < 4; ++u) {
                acc[0] = fmaf(wt[u], bf2f((unsigned short)(v[u] & 0xffffu)), acc[0]);
                acc[1] = fmaf(wt[u], bf2f((unsigned short)(v[u] >> 16)), acc[1]);
            }
        } else {
            ushort4 v[4];
            #pragma unroll
            for (int u = 0; u < 4; ++u)
                v[u] = *(const ushort4*)(xsrc + (size_t)idx[u] * D + lane * 4);
            #pragma unroll
            for (int u = 0; u < 4; ++u) {
                acc[0] = fmaf(wt[u], bf2f(v[u].x), acc[0]);
                acc[1] = fmaf(wt[u], bf2f(v[u].y), acc[1]);
                acc[2] = fmaf(wt[u], bf2f(v[u].z), acc[2]);
                acc[3] = fmaf(wt[u], bf2f(v[u].w), acc[3]);
            }
        }
    }
    float inv = 1.0f / fmaxf((float)(end - beg), 1.0f);
    if constexpr (C == 2) {
        unsigned int p = ((unsigned int)f2bf(acc[1] * inv) << 16) | f2bf(acc[0] * inv);
        *(unsigned int*)(mean + (size_t)w * D + lane * 2) = p;
    } else {
        ushort4 p;
        p.x = f2bf(acc[0] * inv); p.y = f2bf(acc[1] * inv);
        p.z = f2bf(acc[2] * inv); p.w = f2bf(acc[3] * inv);
        *(ushort4*)(mean + (size_t)w * D + lane * 4) = p;
    }
}

// ---------------- one-time weight transpose + bf16 convert ----------------
// W[k][c] f32  ->  Wt[c][k] bf16

__global__ void transpose_w(const float* __restrict__ W, unsigned short* __restrict__ Wt, int D) {
    int wg = blockIdx.x * 4 + (threadIdx.x >> 6);
    int lane = threadIdx.x & 63;
    int kchunks = D >> 6;
    int c = wg / kchunks;
    int kc = wg - c * kchunks;
    int k = kc * 64 + lane;
    if (c < 256) Wt[(size_t)c * D + k] = f2bf(W[(size_t)k * 256 + c]);
}

// ------- fused MFMA dual-GEMM + bias + L2-normalize + leaky_relu -------
// out[n,256] = lrelu(normalize(A@Wl + bias + X@Wr))
// A, X bf16 [n x D]; Wtl/Wtr bf16 transposed [col][k]; output fp32 or bf16.

template <int D, bool BF16OUT>
__global__ __launch_bounds__(256)
void mfma_gemm_norm_lrelu(const unsigned short* __restrict__ A,
                          const unsigned short* __restrict__ X,
                          const unsigned short* __restrict__ Wtl,
                          const unsigned short* __restrict__ Wtr,
                          const float* __restrict__ bias,
                          float* __restrict__ outf, unsigned short* __restrict__ outb, int n) {
    constexpr int BM = 64, BK = 32;
    constexpr int PITCH = 40;   // ushorts per LDS row (80 B) -> only 2-way bank aliasing
    __shared__ __align__(16) unsigned short Asl[BM * PITCH];     //  5 KB
    __shared__ __align__(16) unsigned short Wsl[256 * PITCH];    // 20 KB
    __shared__ float red[4][BM];
    __shared__ float invn[BM];

    const int tid = threadIdx.x;
    const int wid = tid >> 6;      // 4 waves, each owns a 64-col block
    const int lane = tid & 63;
    const int cl = lane & 15;
    const int g = lane >> 4;
    const int row0 = blockIdx.x * BM;

    f32x4 acc[4][4];               // [m: 16-row frag][nn: 16-col frag]
    #pragma unroll
    for (int m = 0; m < 4; ++m)
        #pragma unroll
        for (int nn = 0; nn < 4; ++nn)
            acc[m][nn] = (f32x4){0.f, 0.f, 0.f, 0.f};

    #pragma unroll
    for (int pass = 0; pass < 2; ++pass) {
        const unsigned short* __restrict__ M = pass ? X : A;
        const unsigned short* __restrict__ Wt = pass ? Wtr : Wtl;
        for (int k0 = 0; k0 < D; k0 += BK) {
            __syncthreads();
            // stage M tile: 64 rows x 32 k (bf16), one 16B load per thread
            {
                int r = tid >> 2;
                int kq = (tid & 3) << 3;
                short8 v = {0, 0, 0, 0, 0, 0, 0, 0};
                if (row0 + r < n)
                    v = *(const short8*)(M + (size_t)(row0 + r) * D + k0 + kq);
                *(short8*)(&Asl[r * PITCH + kq]) = v;
            }
            // stage W tile: 256 cols x 32 k (bf16)
            #pragma unroll
            for (int q = 0; q < 4; ++q) {
                int idx = tid + q * 256;          // 0..1023 16B units
                int c = idx >> 2;
                int kq = (idx & 3) << 3;
                *(float4*)(&Wsl[c * PITCH + kq]) =
                    *(const float4*)(Wt + (size_t)c * D + k0 + kq);
            }
            __syncthreads();
            short8 af[4], bfr[4];
            const int g8 = g * 8;
            #pragma unroll
            for (int m = 0; m < 4; ++m)
                af[m] = *(const short8*)(&Asl[(m * 16 + cl) * PITCH + g8]);
            #pragma unroll
            for (int nn = 0; nn < 4; ++nn)
                bfr[nn] = *(const short8*)(&Wsl[(wid * 64 + nn * 16 + cl) * PITCH + g8]);
            #pragma unroll
            for (int m = 0; m < 4; ++m)
                #pragma unroll
                for (int nn = 0; nn < 4; ++nn)
                    acc[m][nn] = __builtin_amdgcn_mfma_f32_16x16x32_bf16(
                        af[m], bfr[nn], acc[m][nn], 0, 0, 0);
        }
    }

    // ---- epilogue: bias, row L2-norm, leaky-relu ----
    float bv[4];
    #pragma unroll
    for (int nn = 0; nn < 4; ++nn) bv[nn] = bias[wid * 64 + nn * 16 + cl];

    float ss[4][4];
    #pragma unroll
    for (int m = 0; m < 4; ++m)
        #pragma unroll
        for (int r = 0; r < 4; ++r) {
            float s = 0.f;
            #pragma unroll
            for (int nn = 0; nn < 4; ++nn) {
                acc[m][nn][r] += bv[nn];
                s = fmaf(acc[m][nn][r], acc[m][nn][r], s);
            }
            ss[m][r] = s;
        }
    #pragma unroll
    for (int mask = 1; mask < 16; mask <<= 1)
        #pragma unroll
        for (int m = 0; m < 4; ++m)
            #pragma unroll
            for (int r = 0; r < 4; ++r)
                ss[m][r] += __shfl_xor(ss[m][r], mask, 64);
    if (cl == 0) {
        #pragma unroll
        for (int m = 0; m < 4; ++m)
            #pragma unroll
            for (int r = 0; r < 4; ++r)
                red[wid][m * 16 + g * 4 + r] = ss[m][r];
    }
    __syncthreads();
    if (tid < BM) {
        float tot = red[0][tid] + red[1][tid] + red[2][tid] + red[3][tid];
        invn[tid] = 1.0f / fmaxf(sqrtf(tot), 1e-12f);
    }
    __syncthreads();
    #pragma unroll
    for (int m = 0; m < 4; ++m)
        #pragma unroll
        for (int r = 0; r < 4; ++r) {
            int row = m * 16 + g * 4 + r;
            if (row0 + row < n) {
                float iv = invn[row];
                #pragma unroll
                for (int nn = 0; nn < 4; ++nn) {
                    float o = lrelu(acc[m][nn][r] * iv);
                    size_t off = (size_t)(row0 + row) * HID_N + wid * 64 + nn * 16 + cl;
                    if constexpr (BF16OUT) outb[off] = f2bf(o);
                    else outf[off] = o;
                }
            }
        }
}

// ---------------- launcher ----------------

extern "C" void kernel_launch(void* const* d_in, const int* in_sizes, int n_in,
                              void* d_out, int out_size, void* d_ws, size_t ws_size,
                              hipStream_t stream) {
    const float* xa = (const float*)d_in[0];
    const float* xb = (const float*)d_in[1];
    const int* ei_ab = (const int*)d_in[2];
    const int* ei_ba = (const int*)d_in[3];
    const float* Wl0_ab = (const float*)d_in[4];
    const float* Wr0_ab = (const float*)d_in[5];
    const float* b0_ab = (const float*)d_in[6];
    const float* Wl0_ba = (const float*)d_in[7];
    const float* Wr0_ba = (const float*)d_in[8];
    const float* b0_ba = (const float*)d_in[9];
    const float* Wl1_ab = (const float*)d_in[10];
    const float* Wr1_ab = (const float*)d_in[11];
    const float* b1_ab = (const float*)d_in[12];
    const float* Wl1_ba = (const float*)d_in[13];
    const float* Wr1_ba = (const float*)d_in[14];
    const float* b1_ba = (const float*)d_in[15];

    float* out_a = (float*)d_out;
    float* out_b = out_a + (size_t)NA_N * HID_N;

    char* w = (char*)d_ws;
    auto carve = [&](size_t bytes) -> char* {
        char* p = w;
        w += (bytes + 255) & ~(size_t)255;
        return p;
    };
    unsigned short* agg1 = (unsigned short*)carve((size_t)NB_N * HID_N * 2);  // mean, dst=b
    unsigned short* agg2 = (unsigned short*)carve((size_t)NA_N * HID_N * 2);  // mean, dst=a
    unsigned short* xa_bf = (unsigned short*)carve((size_t)NA_N * DIN_N * 2);
    unsigned short* xb_bf = (unsigned short*)carve((size_t)NB_N * DIN_N * 2);
    unsigned short* ha_bf = (unsigned short*)carve((size_t)NA_N * HID_N * 2);
    unsigned short* hb_bf = (unsigned short*)carve((size_t)NB_N * HID_N * 2);
    int* cnt_b = (int*)carve((size_t)NB_N * 4);
    int* cnt_a = (int*)carve((size_t)NA_N * 4);
    int* off_b = (int*)carve((size_t)(NB_N + 1) * 4);
    int* off_a = (int*)carve((size_t)(NA_N + 1) * 4);
    int* cur_b = (int*)carve((size_t)NB_N * 4);
    int* cur_a = (int*)carve((size_t)NA_N * 4);
    int* bsum = (int*)carve(256 * 4);
    int* boff = (int*)carve(256 * 4);
    int* ssrc_ab = (int*)carve((size_t)NE_N * 4);
    int* ssrc_ba = (int*)carve((size_t)NE_N * 4);
    unsigned short* wt_l0ab = (unsigned short*)carve((size_t)DIN_N * 256 * 2);
    unsigned short* wt_r0ab = (unsigned short*)carve((size_t)DIN_N * 256 * 2);
    unsigned short* wt_l0ba = (unsigned short*)carve((size_t)DIN_N * 256 * 2);
    unsigned short* wt_r0ba = (unsigned short*)carve((size_t)DIN_N * 256 * 2);
    unsigned short* wt_l1ab = (unsigned short*)carve((size_t)HID_N * 256 * 2);
    unsigned short* wt_r1ab = (unsigned short*)carve((size_t)HID_N * 256 * 2);
    unsigned short* wt_l1ba = (unsigned short*)carve((size_t)HID_N * 256 * 2);
    unsigned short* wt_r1ba = (unsigned short*)carve((size_t)HID_N * 256 * 2);

    hipMemsetAsync(cnt_b, 0, NB_N * 4, stream);
    hipMemsetAsync(cnt_a, 0, NA_N * 4, stream);
    hipMemsetAsync(cur_b, 0, NB_N * 4, stream);
    hipMemsetAsync(cur_a, 0, NA_N * 4, stream);

    // bf16 copies of inputs
    f2bf_arr<<<(NA_N * DIN_N / 4 + 255) / 256, 256, 0, stream>>>(xa, xa_bf, NA_N * DIN_N / 4);
    f2bf_arr<<<(NB_N * DIN_N / 4 + 255) / 256, 256, 0, stream>>>(xb, xb_bf, NB_N * DIN_N / 4);

    // one-time weight transposes (bf16)
    transpose_w<<<128, 256, 0, stream>>>(Wl0_ab, wt_l0ab, DIN_N);
    transpose_w<<<128, 256, 0, stream>>>(Wr0_ab, wt_r0ab, DIN_N);
    transpose_w<<<128, 256, 0, stream>>>(Wl0_ba, wt_l0ba, DIN_N);
    transpose_w<<<128, 256, 0, stream>>>(Wr0_ba, wt_r0ba, DIN_N);
    transpose_w<<<256, 256, 0, stream>>>(Wl1_ab, wt_l1ab, HID_N);
    transpose_w<<<256, 256, 0, stream>>>(Wr1_ab, wt_r1ab, HID_N);
    transpose_w<<<256, 256, 0, stream>>>(Wl1_ba, wt_l1ba, HID_N);
    transpose_w<<<256, 256, 0, stream>>>(Wr1_ba, wt_r1ba, HID_N);

    const int eb = (NE_N + 255) / 256;
    hist_kernel<<<eb, 256, 0, stream>>>(ei_ab + NE_N, NE_N, cnt_b);
    hist_kernel<<<eb, 256, 0, stream>>>(ei_ba + NE_N, NE_N, cnt_a);

    const int nchunk_b = (NB_N + 255) / 256;
    scan_partial<<<nchunk_b, 256, 0, stream>>>(cnt_b, NB_N, bsum);
    scan_block<<<1, 256, 0, stream>>>(bsum, nchunk_b, boff);
    scan_final<<<nchunk_b, 256, 0, stream>>>(cnt_b, NB_N, boff, off_b);

    const int nchunk_a = (NA_N + 255) / 256;
    scan_partial<<<nchunk_a, 256, 0, stream>>>(cnt_a, NA_N, bsum);
    scan_block<<<1, 256, 0, stream>>>(bsum, nchunk_a, boff);
    scan_final<<<nchunk_a, 256, 0, stream>>>(cnt_a, NA_N, boff, off_a);

    scatter_kernel<<<eb, 256, 0, stream>>>(ei_ab, ei_ab + NE_N, NE_N, off_b, cur_b, ssrc_ab);
    scatter_kernel<<<eb, 256, 0, stream>>>(ei_ba, ei_ba + NE_N, NE_N, off_a, cur_a, ssrc_ba);

    const int gb = (NB_N + 63) / 64;
    const int ga = (NA_N + 63) / 64;
    const int ab4 = (NA_N + 3) / 4;
    const int bb4 = (NB_N + 3) / 4;

    // ---- layer 0 (D = 128): h written as bf16 only ----
    agg_mean_bf<2><<<bb4, 256, 0, stream>>>(xa_bf, ssrc_ab, off_b, agg1, NB_N);
    mfma_gemm_norm_lrelu<DIN_N, true><<<gb, 256, 0, stream>>>(
        agg1, xb_bf, wt_l0ab, wt_r0ab, b0_ab, nullptr, hb_bf, NB_N);
    agg_mean_bf<2><<<ab4, 256, 0, stream>>>(xb_bf, ssrc_ba, off_a, agg2, NA_N);
    mfma_gemm_norm_lrelu<DIN_N, true><<<ga, 256, 0, stream>>>(
        agg2, xa_bf, wt_l0ba, wt_r0ba, b0_ba, nullptr, ha_bf, NA_N);

    // ---- layer 1 (D = 256): fp32 final outputs ----
    agg_mean_bf<4><<<bb4, 256, 0, stream>>>(ha_bf, ssrc_ab, off_b, agg1, NB_N);
    agg_mean_bf<4><<<ab4, 256, 0, stream>>>(hb_bf, ssrc_ba, off_a, agg2, NA_N);
    mfma_gemm_norm_lrelu<HID_N, false><<<gb, 256, 0, stream>>>(
        agg1, hb_bf, wt_l1ab, wt_r1ab, b1_ab, out_b, nullptr, NB_N);
    mfma_gemm_norm_lrelu<HID_N, false><<<ga, 256, 0, stream>>>(
        agg2, ha_bf, wt_l1ba, wt_r1ba, b1_ba, out_a, nullptr, NA_N);
}

// Round 4
// 495.045 us; speedup vs baseline: 3.0696x; 1.2023x over previous
//
#include <hip/hip_runtime.h>
#include <hip/hip_bf16.h>
#include <math.h>
#include <string.h>

#define NA_N 50000
#define NB_N 50000
#define DIN_N 128
#define HID_N 256
#define NE_N 1000000

#define BSHIFT 9
#define BSIZE (1 << BSHIFT)                        // 512 dsts per bucket
#define NBUCK ((NA_N + BSIZE - 1) >> BSHIFT)       // 98
#define CHUNK 4096

typedef short short8 __attribute__((ext_vector_type(8)));
typedef float f32x4 __attribute__((ext_vector_type(4)));

static __device__ __forceinline__ float lrelu(float x) {
    return x >= 0.0f ? x : 0.01f * x;
}

static __device__ __forceinline__ unsigned short f2bf(float f) {
    __hip_bfloat16 h = __float2bfloat16(f);   // RNE
    unsigned short u;
    memcpy(&u, &h, 2);
    return u;
}

static __device__ __forceinline__ float bf2f(unsigned short u) {
    unsigned int x = ((unsigned int)u) << 16;
    float f;
    memcpy(&f, &x, 4);
    return f;
}

// ---------------- fp32 -> bf16 convert (two arrays in one launch) ----------------

__global__ void f2bf_arr2(const float* __restrict__ inA, unsigned short* __restrict__ outA,
                          const float* __restrict__ inB, unsigned short* __restrict__ outB, int n4) {
    int i = blockIdx.x * blockDim.x + threadIdx.x;
    const float* in = blockIdx.y ? inB : inA;
    unsigned short* out = blockIdx.y ? outB : outA;
    if (i < n4) {
        float4 v = ((const float4*)in)[i];
        ushort4 b;
        b.x = f2bf(v.x); b.y = f2bf(v.y); b.z = f2bf(v.z); b.w = f2bf(v.w);
        ((ushort4*)out)[i] = b;
    }
}

// ---------------- bucketed CSR build ----------------
// coarse: bucket = dst >> BSHIFT (98 buckets)

__global__ __launch_bounds__(256)
void coarse_hist(const int* __restrict__ dst, int E, int* __restrict__ ghist) {
    __shared__ int lc[NBUCK];
    for (int i = threadIdx.x; i < NBUCK; i += 256) lc[i] = 0;
    __syncthreads();
    int base = blockIdx.x * CHUNK;
    int end = min(base + CHUNK, E);
    for (int i = base + threadIdx.x; i < end; i += 256)
        atomicAdd(&lc[dst[i] >> BSHIFT], 1);
    __syncthreads();
    for (int i = threadIdx.x; i < NBUCK; i += 256)
        if (lc[i]) atomicAdd(&ghist[i], lc[i]);
}

// 1 block, 128 threads: exclusive scan of 98 bucket counts -> cbase[99], cursor[98]
__global__ void bucket_scan(const int* __restrict__ ghist, int* __restrict__ cbase,
                            int* __restrict__ cursor) {
    int tid = threadIdx.x;
    int v = (tid < NBUCK) ? ghist[tid] : 0;
    int incl = v;
    #pragma unroll
    for (int m = 1; m < 64; m <<= 1) {
        int o = __shfl_up(incl, m, 64);
        if ((tid & 63) >= m) incl += o;
    }
    __shared__ int wsum[2];
    if ((tid & 63) == 63) wsum[tid >> 6] = incl;
    __syncthreads();
    if (tid >= 64) incl += wsum[0];
    if (tid < NBUCK) {
        cbase[tid] = incl - v;
        cursor[tid] = incl - v;
    }
    if (tid == 127) cbase[NBUCK] = incl;   // total = E
}

__global__ __launch_bounds__(256)
void coarse_scatter(const int* __restrict__ src, const int* __restrict__ dst, int E,
                    int* __restrict__ cursor, unsigned long long* __restrict__ bucketed) {
    __shared__ int lc[NBUCK];
    __shared__ int gb[NBUCK];
    for (int i = threadIdx.x; i < NBUCK; i += 256) lc[i] = 0;
    __syncthreads();
    int base = blockIdx.x * CHUNK;
    int end = min(base + CHUNK, E);
    for (int i = base + threadIdx.x; i < end; i += 256)
        atomicAdd(&lc[dst[i] >> BSHIFT], 1);
    __syncthreads();
    for (int i = threadIdx.x; i < NBUCK; i += 256) {
        int c = lc[i];
        gb[i] = c ? atomicAdd(&cursor[i], c) : 0;
        lc[i] = 0;                      // reuse as local cursor
    }
    __syncthreads();
    for (int i = base + threadIdx.x; i < end; i += 256) {
        int d = dst[i];
        int bk = d >> BSHIFT;
        int p = atomicAdd(&lc[bk], 1);
        bucketed[(size_t)gb[bk] + p] = ((unsigned long long)(unsigned int)d << 32) |
                                       (unsigned int)src[i];
    }
}

// one block per bucket: LDS per-dst hist + scan -> offs[] and in-bucket scatter of src
__global__ __launch_bounds__(256)
void fine_scatter(const unsigned long long* __restrict__ bucketed, const int* __restrict__ cbase,
                  int n, int E, int* __restrict__ offs, int* __restrict__ ssrc) {
    int bk = blockIdx.x;
    int ebeg = cbase[bk], eend = cbase[bk + 1];
    int d0 = bk << BSHIFT;
    __shared__ int dc[BSIZE];
    __shared__ int wp[4];
    int tid = threadIdx.x;
    for (int i = tid; i < BSIZE; i += 256) dc[i] = 0;
    __syncthreads();
    for (int i = ebeg + tid; i < eend; i += 256) {
        int dl = (int)(bucketed[i] >> 32) - d0;
        atomicAdd(&dc[dl], 1);
    }
    __syncthreads();
    // exclusive scan of dc[512]: each thread owns 2 consecutive entries
    int a = dc[2 * tid], b = dc[2 * tid + 1];
    int s = a + b;
    int incl = s;
    #pragma unroll
    for (int m = 1; m < 64; m <<= 1) {
        int o = __shfl_up(incl, m, 64);
        if ((tid & 63) >= m) incl += o;
    }
    if ((tid & 63) == 63) wp[tid >> 6] = incl;
    __syncthreads();
    int add = 0;
    for (int w0 = 0; w0 < (tid >> 6); ++w0) add += wp[w0];
    incl += add;
    int excl = incl - s;
    dc[2 * tid] = excl;
    dc[2 * tid + 1] = excl + a;
    int d = d0 + 2 * tid;
    if (d < n) offs[d] = ebeg + excl;
    if (d + 1 < n) offs[d + 1] = ebeg + excl + a;
    if (bk == (int)gridDim.x - 1 && tid == 0) offs[n] = E;
    __syncthreads();
    // scatter src using dc as running cursors (writes stay in this bucket's window)
    for (int i = ebeg + tid; i < eend; i += 256) {
        unsigned long long e = bucketed[i];
        int dl = (int)(e >> 32) - d0;
        int p = atomicAdd(&dc[dl], 1);
        ssrc[ebeg + p] = (int)(e & 0xffffffffu);
    }
}

// -------- aggregation: one wave per destination, 4-deep gather pipeline --------

template <int C>
__global__ __launch_bounds__(256)
void agg_mean_bf(const unsigned short* __restrict__ xsrc, const int* __restrict__ ssrc,
                 const int* __restrict__ offs, unsigned short* __restrict__ mean, int n) {
    constexpr int D = C * 64;
    int w = blockIdx.x * 4 + (threadIdx.x >> 6);
    int lane = threadIdx.x & 63;
    if (w >= n) return;
    int beg = offs[w], end = offs[w + 1];
    float acc[C];
    #pragma unroll
    for (int c = 0; c < C; ++c) acc[c] = 0.0f;

    for (int e = beg; e < end; e += 4) {
        int idx[4];
        float wt[4];
        #pragma unroll
        for (int u = 0; u < 4; ++u) {
            int ee = e + u;
            idx[u] = ssrc[ee < end ? ee : end - 1];
            wt[u] = (ee < end) ? 1.0f : 0.0f;
        }
        if constexpr (C == 2) {
            unsigned int v[4];
            #pragma unroll
            for (int u = 0; u < 4; ++u)
                v[u] = *(const unsigned int*)(xsrc + (size_t)idx[u] * D + lane * 2);
            #pragma unroll
            for (int u = 0; u < 4; ++u) {
                acc[0] = fmaf(wt[u], bf2f((unsigned short)(v[u] & 0xffffu)), acc[0]);
                acc[1] = fmaf(wt[u], bf2f((unsigned short)(v[u] >> 16)), acc[1]);
            }
        } else {
            ushort4 v[4];
            #pragma unroll
            for (int u = 0; u < 4; ++u)
                v[u] = *(const ushort4*)(xsrc + (size_t)idx[u] * D + lane * 4);
            #pragma unroll
            for (int u = 0; u < 4; ++u) {
                acc[0] = fmaf(wt[u], bf2f(v[u].x), acc[0]);
                acc[1] = fmaf(wt[u], bf2f(v[u].y), acc[1]);
                acc[2] = fmaf(wt[u], bf2f(v[u].z), acc[2]);
                acc[3] = fmaf(wt[u], bf2f(v[u].w), acc[3]);
            }
        }
    }
    float inv = 1.0f / fmaxf((float)(end - beg), 1.0f);
    if constexpr (C == 2) {
        unsigned int p = ((unsigned int)f2bf(acc[1] * inv) << 16) | f2bf(acc[0] * inv);
        *(unsigned int*)(mean + (size_t)w * D + lane * 2) = p;
    } else {
        ushort4 p;
        p.x = f2bf(acc[0] * inv); p.y = f2bf(acc[1] * inv);
        p.z = f2bf(acc[2] * inv); p.w = f2bf(acc[3] * inv);
        *(ushort4*)(mean + (size_t)w * D + lane * 4) = p;
    }
}

// ---------------- weight transpose + bf16 convert (4 weights per launch) ----------------
// W[k][c] f32  ->  Wt[c][k] bf16 ; blockIdx.y selects which of 4 weight matrices

__global__ void transpose_w4(const float* __restrict__ W0, unsigned short* __restrict__ T0,
                             const float* __restrict__ W1, unsigned short* __restrict__ T1,
                             const float* __restrict__ W2, unsigned short* __restrict__ T2,
                             const float* __restrict__ W3, unsigned short* __restrict__ T3,
                             int D) {
    const float* W = blockIdx.y == 0 ? W0 : blockIdx.y == 1 ? W1 : blockIdx.y == 2 ? W2 : W3;
    unsigned short* Wt = blockIdx.y == 0 ? T0 : blockIdx.y == 1 ? T1 : blockIdx.y == 2 ? T2 : T3;
    int wg = blockIdx.x * 4 + (threadIdx.x >> 6);
    int lane = threadIdx.x & 63;
    int kchunks = D >> 6;
    int c = wg / kchunks;
    int kc = wg - c * kchunks;
    int k = kc * 64 + lane;
    if (c < 256) Wt[(size_t)c * D + k] = f2bf(W[(size_t)k * 256 + c]);
}

// ------- fused MFMA dual-GEMM + bias + L2-normalize + leaky_relu -------

template <int D, bool BF16OUT>
__global__ __launch_bounds__(256)
void mfma_gemm_norm_lrelu(const unsigned short* __restrict__ A,
                          const unsigned short* __restrict__ X,
                          const unsigned short* __restrict__ Wtl,
                          const unsigned short* __restrict__ Wtr,
                          const float* __restrict__ bias,
                          float* __restrict__ outf, unsigned short* __restrict__ outb, int n) {
    constexpr int BM = 64, BK = 32;
    constexpr int PITCH = 40;
    __shared__ __align__(16) unsigned short Asl[BM * PITCH];
    __shared__ __align__(16) unsigned short Wsl[256 * PITCH];
    __shared__ float red[4][BM];
    __shared__ float invn[BM];

    const int tid = threadIdx.x;
    const int wid = tid >> 6;
    const int lane = tid & 63;
    const int cl = lane & 15;
    const int g = lane >> 4;
    const int row0 = blockIdx.x * BM;

    f32x4 acc[4][4];
    #pragma unroll
    for (int m = 0; m < 4; ++m)
        #pragma unroll
        for (int nn = 0; nn < 4; ++nn)
            acc[m][nn] = (f32x4){0.f, 0.f, 0.f, 0.f};

    #pragma unroll
    for (int pass = 0; pass < 2; ++pass) {
        const unsigned short* __restrict__ M = pass ? X : A;
        const unsigned short* __restrict__ Wt = pass ? Wtr : Wtl;
        for (int k0 = 0; k0 < D; k0 += BK) {
            __syncthreads();
            {
                int r = tid >> 2;
                int kq = (tid & 3) << 3;
                short8 v = {0, 0, 0, 0, 0, 0, 0, 0};
                if (row0 + r < n)
                    v = *(const short8*)(M + (size_t)(row0 + r) * D + k0 + kq);
                *(short8*)(&Asl[r * PITCH + kq]) = v;
            }
            #pragma unroll
            for (int q = 0; q < 4; ++q) {
                int idx = tid + q * 256;
                int c = idx >> 2;
                int kq = (idx & 3) << 3;
                *(float4*)(&Wsl[c * PITCH + kq]) =
                    *(const float4*)(Wt + (size_t)c * D + k0 + kq);
            }
            __syncthreads();
            short8 af[4], bfr[4];
            const int g8 = g * 8;
            #pragma unroll
            for (int m = 0; m < 4; ++m)
                af[m] = *(const short8*)(&Asl[(m * 16 + cl) * PITCH + g8]);
            #pragma unroll
            for (int nn = 0; nn < 4; ++nn)
                bfr[nn] = *(const short8*)(&Wsl[(wid * 64 + nn * 16 + cl) * PITCH + g8]);
            #pragma unroll
            for (int m = 0; m < 4; ++m)
                #pragma unroll
                for (int nn = 0; nn < 4; ++nn)
                    acc[m][nn] = __builtin_amdgcn_mfma_f32_16x16x32_bf16(
                        af[m], bfr[nn], acc[m][nn], 0, 0, 0);
        }
    }

    float bv[4];
    #pragma unroll
    for (int nn = 0; nn < 4; ++nn) bv[nn] = bias[wid * 64 + nn * 16 + cl];

    float ss[4][4];
    #pragma unroll
    for (int m = 0; m < 4; ++m)
        #pragma unroll
        for (int r = 0; r < 4; ++r) {
            float s = 0.f;
            #pragma unroll
            for (int nn = 0; nn < 4; ++nn) {
                acc[m][nn][r] += bv[nn];
                s = fmaf(acc[m][nn][r], acc[m][nn][r], s);
            }
            ss[m][r] = s;
        }
    #pragma unroll
    for (int mask = 1; mask < 16; mask <<= 1)
        #pragma unroll
        for (int m = 0; m < 4; ++m)
            #pragma unroll
            for (int r = 0; r < 4; ++r)
                ss[m][r] += __shfl_xor(ss[m][r], mask, 64);
    if (cl == 0) {
        #pragma unroll
        for (int m = 0; m < 4; ++m)
            #pragma unroll
            for (int r = 0; r < 4; ++r)
                red[wid][m * 16 + g * 4 + r] = ss[m][r];
    }
    __syncthreads();
    if (tid < BM) {
        float tot = red[0][tid] + red[1][tid] + red[2][tid] + red[3][tid];
        invn[tid] = 1.0f / fmaxf(sqrtf(tot), 1e-12f);
    }
    __syncthreads();
    #pragma unroll
    for (int m = 0; m < 4; ++m)
        #pragma unroll
        for (int r = 0; r < 4; ++r) {
            int row = m * 16 + g * 4 + r;
            if (row0 + row < n) {
                float iv = invn[row];
                #pragma unroll
                for (int nn = 0; nn < 4; ++nn) {
                    float o = lrelu(acc[m][nn][r] * iv);
                    size_t off = (size_t)(row0 + row) * HID_N + wid * 64 + nn * 16 + cl;
                    if constexpr (BF16OUT) outb[off] = f2bf(o);
                    else outf[off] = o;
                }
            }
        }
}

// ---------------- launcher ----------------

extern "C" void kernel_launch(void* const* d_in, const int* in_sizes, int n_in,
                              void* d_out, int out_size, void* d_ws, size_t ws_size,
                              hipStream_t stream) {
    const float* xa = (const float*)d_in[0];
    const float* xb = (const float*)d_in[1];
    const int* ei_ab = (const int*)d_in[2];
    const int* ei_ba = (const int*)d_in[3];
    const float* Wl0_ab = (const float*)d_in[4];
    const float* Wr0_ab = (const float*)d_in[5];
    const float* b0_ab = (const float*)d_in[6];
    const float* Wl0_ba = (const float*)d_in[7];
    const float* Wr0_ba = (const float*)d_in[8];
    const float* b0_ba = (const float*)d_in[9];
    const float* Wl1_ab = (const float*)d_in[10];
    const float* Wr1_ab = (const float*)d_in[11];
    const float* b1_ab = (const float*)d_in[12];
    const float* Wl1_ba = (const float*)d_in[13];
    const float* Wr1_ba = (const float*)d_in[14];
    const float* b1_ba = (const float*)d_in[15];

    float* out_a = (float*)d_out;
    float* out_b = out_a + (size_t)NA_N * HID_N;

    char* w = (char*)d_ws;
    auto carve = [&](size_t bytes) -> char* {
        char* p = w;
        w += (bytes + 255) & ~(size_t)255;
        return p;
    };
    unsigned short* agg1 = (unsigned short*)carve((size_t)NB_N * HID_N * 2);  // 25.6 MB
    unsigned short* agg2 = (unsigned short*)carve((size_t)NA_N * HID_N * 2);  // 25.6 MB
    // bucketed edge arrays alias agg1/agg2 (dead before the aggs run)
    unsigned long long* bucketed_b = (unsigned long long*)agg1;   // 8 MB used
    unsigned long long* bucketed_a = (unsigned long long*)agg2;
    unsigned short* xa_bf = (unsigned short*)carve((size_t)NA_N * DIN_N * 2);
    unsigned short* xb_bf = (unsigned short*)carve((size_t)NB_N * DIN_N * 2);
    unsigned short* ha_bf = (unsigned short*)carve((size_t)NA_N * HID_N * 2);
    unsigned short* hb_bf = (unsigned short*)carve((size_t)NB_N * HID_N * 2);
    int* off_b = (int*)carve((size_t)(NB_N + 1) * 4);
    int* off_a = (int*)carve((size_t)(NA_N + 1) * 4);
    int* ghist_b = (int*)carve(NBUCK * 4);
    int* ghist_a = (int*)carve(NBUCK * 4);
    int* cbase_b = (int*)carve((NBUCK + 1) * 4);
    int* cbase_a = (int*)carve((NBUCK + 1) * 4);
    int* cursor_b = (int*)carve(NBUCK * 4);
    int* cursor_a = (int*)carve(NBUCK * 4);
    int* ssrc_ab = (int*)carve((size_t)NE_N * 4);
    int* ssrc_ba = (int*)carve((size_t)NE_N * 4);
    unsigned short* wt_l0ab = (unsigned short*)carve((size_t)DIN_N * 256 * 2);
    unsigned short* wt_r0ab = (unsigned short*)carve((size_t)DIN_N * 256 * 2);
    unsigned short* wt_l0ba = (unsigned short*)carve((size_t)DIN_N * 256 * 2);
    unsigned short* wt_r0ba = (unsigned short*)carve((size_t)DIN_N * 256 * 2);
    unsigned short* wt_l1ab = (unsigned short*)carve((size_t)HID_N * 256 * 2);
    unsigned short* wt_r1ab = (unsigned short*)carve((size_t)HID_N * 256 * 2);
    unsigned short* wt_l1ba = (unsigned short*)carve((size_t)HID_N * 256 * 2);
    unsigned short* wt_r1ba = (unsigned short*)carve((size_t)HID_N * 256 * 2);

    hipMemsetAsync(ghist_b, 0, NBUCK * 4, stream);
    hipMemsetAsync(ghist_a, 0, NBUCK * 4, stream);

    // bf16 copies of inputs (both in one launch)
    {
        dim3 g((NA_N * DIN_N / 4 + 255) / 256, 2);
        f2bf_arr2<<<g, 256, 0, stream>>>(xa, xa_bf, xb, xb_bf, NA_N * DIN_N / 4);
    }
    // weight transposes (4 per launch)
    {
        dim3 g0(128, 4), g1(256, 4);
        transpose_w4<<<g0, 256, 0, stream>>>(Wl0_ab, wt_l0ab, Wr0_ab, wt_r0ab,
                                             Wl0_ba, wt_l0ba, Wr0_ba, wt_r0ba, DIN_N);
        transpose_w4<<<g1, 256, 0, stream>>>(Wl1_ab, wt_l1ab, Wr1_ab, wt_r1ab,
                                             Wl1_ba, wt_l1ba, Wr1_ba, wt_r1ba, HID_N);
    }

    // ---- bucketed CSR build ----
    const int cgrid = (NE_N + CHUNK - 1) / CHUNK;
    coarse_hist<<<cgrid, 256, 0, stream>>>(ei_ab + NE_N, NE_N, ghist_b);
    coarse_hist<<<cgrid, 256, 0, stream>>>(ei_ba + NE_N, NE_N, ghist_a);
    bucket_scan<<<1, 128, 0, stream>>>(ghist_b, cbase_b, cursor_b);
    bucket_scan<<<1, 128, 0, stream>>>(ghist_a, cbase_a, cursor_a);
    coarse_scatter<<<cgrid, 256, 0, stream>>>(ei_ab, ei_ab + NE_N, NE_N, cursor_b, bucketed_b);
    coarse_scatter<<<cgrid, 256, 0, stream>>>(ei_ba, ei_ba + NE_N, NE_N, cursor_a, bucketed_a);
    fine_scatter<<<NBUCK, 256, 0, stream>>>(bucketed_b, cbase_b, NB_N, NE_N, off_b, ssrc_ab);
    fine_scatter<<<NBUCK, 256, 0, stream>>>(bucketed_a, cbase_a, NA_N, NE_N, off_a, ssrc_ba);

    const int gb = (NB_N + 63) / 64;
    const int ga = (NA_N + 63) / 64;
    const int ab4 = (NA_N + 3) / 4;
    const int bb4 = (NB_N + 3) / 4;

    // ---- layer 0 (D = 128): h written as bf16 only ----
    agg_mean_bf<2><<<bb4, 256, 0, stream>>>(xa_bf, ssrc_ab, off_b, agg1, NB_N);
    mfma_gemm_norm_lrelu<DIN_N, true><<<gb, 256, 0, stream>>>(
        agg1, xb_bf, wt_l0ab, wt_r0ab, b0_ab, nullptr, hb_bf, NB_N);
    agg_mean_bf<2><<<ab4, 256, 0, stream>>>(xb_bf, ssrc_ba, off_a, agg2, NA_N);
    mfma_gemm_norm_lrelu<DIN_N, true><<<ga, 256, 0, stream>>>(
        agg2, xa_bf, wt_l0ba, wt_r0ba, b0_ba, nullptr, ha_bf, NA_N);

    // ---- layer 1 (D = 256): fp32 final outputs ----
    agg_mean_bf<4><<<bb4, 256, 0, stream>>>(ha_bf, ssrc_ab, off_b, agg1, NB_N);
    agg_mean_bf<4><<<ab4, 256, 0, stream>>>(hb_bf, ssrc_ba, off_a, agg2, NA_N);
    mfma_gemm_norm_lrelu<HID_N, false><<<gb, 256, 0, stream>>>(
        agg1, hb_bf, wt_l1ab, wt_r1ab, b1_ab, out_b, nullptr, NB_N);
    mfma_gemm_norm_lrelu<HID_N, false><<<ga, 256, 0, stream>>>(
        agg2, ha_bf, wt_l1ba, wt_r1ba, b1_ba, out_a, nullptr, NA_N);
}

// Round 5
// 473.343 us; speedup vs baseline: 3.2103x; 1.0458x over previous
//
#include <hip/hip_runtime.h>
#include <hip/hip_bf16.h>
#include <math.h>
#include <string.h>

#define NA_N 50000
#define NB_N 50000
#define DIN_N 128
#define HID_N 256
#define NE_N 1000000

#define BSHIFT 9
#define BSIZE (1 << BSHIFT)                        // 512 dsts per bucket
#define NBUCK ((NA_N + BSIZE - 1) >> BSHIFT)       // 98
#define CHUNK 4096

typedef short short8 __attribute__((ext_vector_type(8)));
typedef float f32x4 __attribute__((ext_vector_type(4)));
typedef unsigned int uint4v __attribute__((ext_vector_type(4)));

static __device__ __forceinline__ float lrelu(float x) {
    return x >= 0.0f ? x : 0.01f * x;
}

static __device__ __forceinline__ unsigned short f2bf(float f) {
    __hip_bfloat16 h = __float2bfloat16(f);   // RNE
    unsigned short u;
    memcpy(&u, &h, 2);
    return u;
}

static __device__ __forceinline__ float bf2f(unsigned short u) {
    unsigned int x = ((unsigned int)u) << 16;
    float f;
    memcpy(&f, &x, 4);
    return f;
}

// ---------------- fp32 -> bf16 convert (two arrays in one launch) ----------------

__global__ void f2bf_arr2(const float* __restrict__ inA, unsigned short* __restrict__ outA,
                          const float* __restrict__ inB, unsigned short* __restrict__ outB, int n4) {
    int i = blockIdx.x * blockDim.x + threadIdx.x;
    const float* in = blockIdx.y ? inB : inA;
    unsigned short* out = blockIdx.y ? outB : outA;
    if (i < n4) {
        float4 v = ((const float4*)in)[i];
        ushort4 b;
        b.x = f2bf(v.x); b.y = f2bf(v.y); b.z = f2bf(v.z); b.w = f2bf(v.w);
        ((ushort4*)out)[i] = b;
    }
}

// ---------------- bucketed CSR build ----------------

__global__ __launch_bounds__(256)
void coarse_hist(const int* __restrict__ dst, int E, int* __restrict__ ghist) {
    __shared__ int lc[NBUCK];
    for (int i = threadIdx.x; i < NBUCK; i += 256) lc[i] = 0;
    __syncthreads();
    int base = blockIdx.x * CHUNK;
    int end = min(base + CHUNK, E);
    for (int i = base + threadIdx.x; i < end; i += 256)
        atomicAdd(&lc[dst[i] >> BSHIFT], 1);
    __syncthreads();
    for (int i = threadIdx.x; i < NBUCK; i += 256)
        if (lc[i]) atomicAdd(&ghist[i], lc[i]);
}

__global__ void bucket_scan(const int* __restrict__ ghist, int* __restrict__ cbase,
                            int* __restrict__ cursor) {
    int tid = threadIdx.x;
    int v = (tid < NBUCK) ? ghist[tid] : 0;
    int incl = v;
    #pragma unroll
    for (int m = 1; m < 64; m <<= 1) {
        int o = __shfl_up(incl, m, 64);
        if ((tid & 63) >= m) incl += o;
    }
    __shared__ int wsum[2];
    if ((tid & 63) == 63) wsum[tid >> 6] = incl;
    __syncthreads();
    if (tid >= 64) incl += wsum[0];
    if (tid < NBUCK) {
        cbase[tid] = incl - v;
        cursor[tid] = incl - v;
    }
    if (tid == 127) cbase[NBUCK] = incl;   // total = E
}

__global__ __launch_bounds__(256)
void coarse_scatter(const int* __restrict__ src, const int* __restrict__ dst, int E,
                    int* __restrict__ cursor, unsigned long long* __restrict__ bucketed) {
    __shared__ int lc[NBUCK];
    __shared__ int gb[NBUCK];
    for (int i = threadIdx.x; i < NBUCK; i += 256) lc[i] = 0;
    __syncthreads();
    int base = blockIdx.x * CHUNK;
    int end = min(base + CHUNK, E);
    for (int i = base + threadIdx.x; i < end; i += 256)
        atomicAdd(&lc[dst[i] >> BSHIFT], 1);
    __syncthreads();
    for (int i = threadIdx.x; i < NBUCK; i += 256) {
        int c = lc[i];
        gb[i] = c ? atomicAdd(&cursor[i], c) : 0;
        lc[i] = 0;                      // reuse as local cursor
    }
    __syncthreads();
    for (int i = base + threadIdx.x; i < end; i += 256) {
        int d = dst[i];
        int bk = d >> BSHIFT;
        int p = atomicAdd(&lc[bk], 1);
        bucketed[(size_t)gb[bk] + p] = ((unsigned long long)(unsigned int)d << 32) |
                                       (unsigned int)src[i];
    }
}

__global__ __launch_bounds__(256)
void fine_scatter(const unsigned long long* __restrict__ bucketed, const int* __restrict__ cbase,
                  int n, int E, int* __restrict__ offs, int* __restrict__ ssrc) {
    int bk = blockIdx.x;
    int ebeg = cbase[bk], eend = cbase[bk + 1];
    int d0 = bk << BSHIFT;
    __shared__ int dc[BSIZE];
    __shared__ int wp[4];
    int tid = threadIdx.x;
    for (int i = tid; i < BSIZE; i += 256) dc[i] = 0;
    __syncthreads();
    for (int i = ebeg + tid; i < eend; i += 256) {
        int dl = (int)(bucketed[i] >> 32) - d0;
        atomicAdd(&dc[dl], 1);
    }
    __syncthreads();
    int a = dc[2 * tid], b = dc[2 * tid + 1];
    int s = a + b;
    int incl = s;
    #pragma unroll
    for (int m = 1; m < 64; m <<= 1) {
        int o = __shfl_up(incl, m, 64);
        if ((tid & 63) >= m) incl += o;
    }
    if ((tid & 63) == 63) wp[tid >> 6] = incl;
    __syncthreads();
    int add = 0;
    for (int w0 = 0; w0 < (tid >> 6); ++w0) add += wp[w0];
    incl += add;
    int excl = incl - s;
    dc[2 * tid] = excl;
    dc[2 * tid + 1] = excl + a;
    int d = d0 + 2 * tid;
    if (d < n) offs[d] = ebeg + excl;
    if (d + 1 < n) offs[d + 1] = ebeg + excl + a;
    if (bk == (int)gridDim.x - 1 && tid == 0) offs[n] = E;
    __syncthreads();
    for (int i = ebeg + tid; i < eend; i += 256) {
        unsigned long long e = bucketed[i];
        int dl = (int)(e >> 32) - d0;
        int p = atomicAdd(&dc[dl], 1);
        ssrc[ebeg + p] = (int)(e & 0xffffffffu);
    }
}

// -------- aggregation v2: one wave per destination, edge-parallel lane groups --------
// G = D/8 lanes per edge (16B each); EPW = 64/G edges per load step; U steps in flight.

template <int D>
__global__ __launch_bounds__(256)
void agg_mean_bf(const unsigned short* __restrict__ xsrc, const int* __restrict__ ssrc,
                 const int* __restrict__ offs, unsigned short* __restrict__ mean, int n) {
    constexpr int G = D / 8;                 // lanes per edge row
    constexpr int EPW = 64 / G;              // edges per step
    constexpr int U = (D == 256) ? 4 : 3;    // steps in flight
    int w = blockIdx.x * 4 + (threadIdx.x >> 6);
    if (w >= n) return;
    const int lane = threadIdx.x & 63;
    const int grp = lane / G;
    const int pos = lane % G;
    const int beg = offs[w], end = offs[w + 1];

    float acc[8];
    #pragma unroll
    for (int c = 0; c < 8; ++c) acc[c] = 0.0f;

    const unsigned short* base = xsrc + pos * 8;
    for (int e = beg; e < end; e += EPW * U) {
        int idx[U];
        float wt[U];
        #pragma unroll
        for (int u = 0; u < U; ++u) {
            int ee = e + u * EPW + grp;
            idx[u] = ssrc[ee < end ? ee : end - 1];
            wt[u] = (ee < end) ? 1.0f : 0.0f;
        }
        uint4v v[U];
        #pragma unroll
        for (int u = 0; u < U; ++u)
            v[u] = *(const uint4v*)(base + (size_t)idx[u] * D);
        #pragma unroll
        for (int u = 0; u < U; ++u)
            #pragma unroll
            for (int c = 0; c < 4; ++c) {
                unsigned int q = v[u][c];
                acc[2 * c]     = fmaf(wt[u], __uint_as_float(q << 16), acc[2 * c]);
                acc[2 * c + 1] = fmaf(wt[u], __uint_as_float(q & 0xffff0000u), acc[2 * c + 1]);
            }
    }
    // combine edge groups
    #pragma unroll
    for (int m = G; m < 64; m <<= 1)
        #pragma unroll
        for (int c = 0; c < 8; ++c)
            acc[c] += __shfl_xor(acc[c], m, 64);
    if (lane < G) {
        float inv = 1.0f / fmaxf((float)(end - beg), 1.0f);
        uint4v o;
        #pragma unroll
        for (int c = 0; c < 4; ++c)
            o[c] = ((unsigned int)f2bf(acc[2 * c + 1] * inv) << 16) | f2bf(acc[2 * c] * inv);
        *(uint4v*)(mean + (size_t)w * D + pos * 8) = o;
    }
}

// ---------------- weight transpose + bf16 convert (4 weights per launch) ----------------

__global__ void transpose_w4(const float* __restrict__ W0, unsigned short* __restrict__ T0,
                             const float* __restrict__ W1, unsigned short* __restrict__ T1,
                             const float* __restrict__ W2, unsigned short* __restrict__ T2,
                             const float* __restrict__ W3, unsigned short* __restrict__ T3,
                             int D) {
    const float* W = blockIdx.y == 0 ? W0 : blockIdx.y == 1 ? W1 : blockIdx.y == 2 ? W2 : W3;
    unsigned short* Wt = blockIdx.y == 0 ? T0 : blockIdx.y == 1 ? T1 : blockIdx.y == 2 ? T2 : T3;
    int wg = blockIdx.x * 4 + (threadIdx.x >> 6);
    int lane = threadIdx.x & 63;
    int kchunks = D >> 6;
    int c = wg / kchunks;
    int kc = wg - c * kchunks;
    int k = kc * 64 + lane;
    if (c < 256) Wt[(size_t)c * D + k] = f2bf(W[(size_t)k * 256 + c]);
}

// ------- fused MFMA dual-GEMM + bias + L2-normalize + leaky_relu -------

template <int D, bool BF16OUT>
__global__ __launch_bounds__(256)
void mfma_gemm_norm_lrelu(const unsigned short* __restrict__ A,
                          const unsigned short* __restrict__ X,
                          const unsigned short* __restrict__ Wtl,
                          const unsigned short* __restrict__ Wtr,
                          const float* __restrict__ bias,
                          float* __restrict__ outf, unsigned short* __restrict__ outb, int n) {
    constexpr int BM = 64, BK = 32;
    constexpr int PITCH = 40;
    __shared__ __align__(16) unsigned short Asl[BM * PITCH];
    __shared__ __align__(16) unsigned short Wsl[256 * PITCH];
    __shared__ float red[4][BM];
    __shared__ float invn[BM];

    const int tid = threadIdx.x;
    const int wid = tid >> 6;
    const int lane = tid & 63;
    const int cl = lane & 15;
    const int g = lane >> 4;
    const int row0 = blockIdx.x * BM;

    f32x4 acc[4][4];
    #pragma unroll
    for (int m = 0; m < 4; ++m)
        #pragma unroll
        for (int nn = 0; nn < 4; ++nn)
            acc[m][nn] = (f32x4){0.f, 0.f, 0.f, 0.f};

    #pragma unroll
    for (int pass = 0; pass < 2; ++pass) {
        const unsigned short* __restrict__ M = pass ? X : A;
        const unsigned short* __restrict__ Wt = pass ? Wtr : Wtl;
        for (int k0 = 0; k0 < D; k0 += BK) {
            __syncthreads();
            {
                int r = tid >> 2;
                int kq = (tid & 3) << 3;
                short8 v = {0, 0, 0, 0, 0, 0, 0, 0};
                if (row0 + r < n)
                    v = *(const short8*)(M + (size_t)(row0 + r) * D + k0 + kq);
                *(short8*)(&Asl[r * PITCH + kq]) = v;
            }
            #pragma unroll
            for (int q = 0; q < 4; ++q) {
                int idx = tid + q * 256;
                int c = idx >> 2;
                int kq = (idx & 3) << 3;
                *(float4*)(&Wsl[c * PITCH + kq]) =
                    *(const float4*)(Wt + (size_t)c * D + k0 + kq);
            }
            __syncthreads();
            short8 af[4], bfr[4];
            const int g8 = g * 8;
            #pragma unroll
            for (int m = 0; m < 4; ++m)
                af[m] = *(const short8*)(&Asl[(m * 16 + cl) * PITCH + g8]);
            #pragma unroll
            for (int nn = 0; nn < 4; ++nn)
                bfr[nn] = *(const short8*)(&Wsl[(wid * 64 + nn * 16 + cl) * PITCH + g8]);
            #pragma unroll
            for (int m = 0; m < 4; ++m)
                #pragma unroll
                for (int nn = 0; nn < 4; ++nn)
                    acc[m][nn] = __builtin_amdgcn_mfma_f32_16x16x32_bf16(
                        af[m], bfr[nn], acc[m][nn], 0, 0, 0);
        }
    }

    float bv[4];
    #pragma unroll
    for (int nn = 0; nn < 4; ++nn) bv[nn] = bias[wid * 64 + nn * 16 + cl];

    float ss[4][4];
    #pragma unroll
    for (int m = 0; m < 4; ++m)
        #pragma unroll
        for (int r = 0; r < 4; ++r) {
            float s = 0.f;
            #pragma unroll
            for (int nn = 0; nn < 4; ++nn) {
                acc[m][nn][r] += bv[nn];
                s = fmaf(acc[m][nn][r], acc[m][nn][r], s);
            }
            ss[m][r] = s;
        }
    #pragma unroll
    for (int mask = 1; mask < 16; mask <<= 1)
        #pragma unroll
        for (int m = 0; m < 4; ++m)
            #pragma unroll
            for (int r = 0; r < 4; ++r)
                ss[m][r] += __shfl_xor(ss[m][r], mask, 64);
    if (cl == 0) {
        #pragma unroll
        for (int m = 0; m < 4; ++m)
            #pragma unroll
            for (int r = 0; r < 4; ++r)
                red[wid][m * 16 + g * 4 + r] = ss[m][r];
    }
    __syncthreads();
    if (tid < BM) {
        float tot = red[0][tid] + red[1][tid] + red[2][tid] + red[3][tid];
        invn[tid] = 1.0f / fmaxf(sqrtf(tot), 1e-12f);
    }
    __syncthreads();
    #pragma unroll
    for (int m = 0; m < 4; ++m)
        #pragma unroll
        for (int r = 0; r < 4; ++r) {
            int row = m * 16 + g * 4 + r;
            if (row0 + row < n) {
                float iv = invn[row];
                #pragma unroll
                for (int nn = 0; nn < 4; ++nn) {
                    float o = lrelu(acc[m][nn][r] * iv);
                    size_t off = (size_t)(row0 + row) * HID_N + wid * 64 + nn * 16 + cl;
                    if constexpr (BF16OUT) outb[off] = f2bf(o);
                    else outf[off] = o;
                }
            }
        }
}

// ---------------- launcher ----------------

extern "C" void kernel_launch(void* const* d_in, const int* in_sizes, int n_in,
                              void* d_out, int out_size, void* d_ws, size_t ws_size,
                              hipStream_t stream) {
    const float* xa = (const float*)d_in[0];
    const float* xb = (const float*)d_in[1];
    const int* ei_ab = (const int*)d_in[2];
    const int* ei_ba = (const int*)d_in[3];
    const float* Wl0_ab = (const float*)d_in[4];
    const float* Wr0_ab = (const float*)d_in[5];
    const float* b0_ab = (const float*)d_in[6];
    const float* Wl0_ba = (const float*)d_in[7];
    const float* Wr0_ba = (const float*)d_in[8];
    const float* b0_ba = (const float*)d_in[9];
    const float* Wl1_ab = (const float*)d_in[10];
    const float* Wr1_ab = (const float*)d_in[11];
    const float* b1_ab = (const float*)d_in[12];
    const float* Wl1_ba = (const float*)d_in[13];
    const float* Wr1_ba = (const float*)d_in[14];
    const float* b1_ba = (const float*)d_in[15];

    float* out_a = (float*)d_out;
    float* out_b = out_a + (size_t)NA_N * HID_N;

    char* w = (char*)d_ws;
    auto carve = [&](size_t bytes) -> char* {
        char* p = w;
        w += (bytes + 255) & ~(size_t)255;
        return p;
    };
    unsigned short* agg1 = (unsigned short*)carve((size_t)NB_N * HID_N * 2);
    unsigned short* agg2 = (unsigned short*)carve((size_t)NA_N * HID_N * 2);
    unsigned long long* bucketed_b = (unsigned long long*)agg1;   // aliases agg1 (dead before aggs)
    unsigned long long* bucketed_a = (unsigned long long*)agg2;
    unsigned short* xa_bf = (unsigned short*)carve((size_t)NA_N * DIN_N * 2);
    unsigned short* xb_bf = (unsigned short*)carve((size_t)NB_N * DIN_N * 2);
    unsigned short* ha_bf = (unsigned short*)carve((size_t)NA_N * HID_N * 2);
    unsigned short* hb_bf = (unsigned short*)carve((size_t)NB_N * HID_N * 2);
    int* off_b = (int*)carve((size_t)(NB_N + 1) * 4);
    int* off_a = (int*)carve((size_t)(NA_N + 1) * 4);
    int* ghist_b = (int*)carve(NBUCK * 4);
    int* ghist_a = (int*)carve(NBUCK * 4);
    int* cbase_b = (int*)carve((NBUCK + 1) * 4);
    int* cbase_a = (int*)carve((NBUCK + 1) * 4);
    int* cursor_b = (int*)carve(NBUCK * 4);
    int* cursor_a = (int*)carve(NBUCK * 4);
    int* ssrc_ab = (int*)carve((size_t)NE_N * 4);
    int* ssrc_ba = (int*)carve((size_t)NE_N * 4);
    unsigned short* wt_l0ab = (unsigned short*)carve((size_t)DIN_N * 256 * 2);
    unsigned short* wt_r0ab = (unsigned short*)carve((size_t)DIN_N * 256 * 2);
    unsigned short* wt_l0ba = (unsigned short*)carve((size_t)DIN_N * 256 * 2);
    unsigned short* wt_r0ba = (unsigned short*)carve((size_t)DIN_N * 256 * 2);
    unsigned short* wt_l1ab = (unsigned short*)carve((size_t)HID_N * 256 * 2);
    unsigned short* wt_r1ab = (unsigned short*)carve((size_t)HID_N * 256 * 2);
    unsigned short* wt_l1ba = (unsigned short*)carve((size_t)HID_N * 256 * 2);
    unsigned short* wt_r1ba = (unsigned short*)carve((size_t)HID_N * 256 * 2);

    hipMemsetAsync(ghist_b, 0, NBUCK * 4, stream);
    hipMemsetAsync(ghist_a, 0, NBUCK * 4, stream);

    {
        dim3 g((NA_N * DIN_N / 4 + 255) / 256, 2);
        f2bf_arr2<<<g, 256, 0, stream>>>(xa, xa_bf, xb, xb_bf, NA_N * DIN_N / 4);
    }
    {
        dim3 g0(128, 4), g1(256, 4);
        transpose_w4<<<g0, 256, 0, stream>>>(Wl0_ab, wt_l0ab, Wr0_ab, wt_r0ab,
                                             Wl0_ba, wt_l0ba, Wr0_ba, wt_r0ba, DIN_N);
        transpose_w4<<<g1, 256, 0, stream>>>(Wl1_ab, wt_l1ab, Wr1_ab, wt_r1ab,
                                             Wl1_ba, wt_l1ba, Wr1_ba, wt_r1ba, HID_N);
    }

    const int cgrid = (NE_N + CHUNK - 1) / CHUNK;
    coarse_hist<<<cgrid, 256, 0, stream>>>(ei_ab + NE_N, NE_N, ghist_b);
    coarse_hist<<<cgrid, 256, 0, stream>>>(ei_ba + NE_N, NE_N, ghist_a);
    bucket_scan<<<1, 128, 0, stream>>>(ghist_b, cbase_b, cursor_b);
    bucket_scan<<<1, 128, 0, stream>>>(ghist_a, cbase_a, cursor_a);
    coarse_scatter<<<cgrid, 256, 0, stream>>>(ei_ab, ei_ab + NE_N, NE_N, cursor_b, bucketed_b);
    coarse_scatter<<<cgrid, 256, 0, stream>>>(ei_ba, ei_ba + NE_N, NE_N, cursor_a, bucketed_a);
    fine_scatter<<<NBUCK, 256, 0, stream>>>(bucketed_b, cbase_b, NB_N, NE_N, off_b, ssrc_ab);
    fine_scatter<<<NBUCK, 256, 0, stream>>>(bucketed_a, cbase_a, NA_N, NE_N, off_a, ssrc_ba);

    const int gb = (NB_N + 63) / 64;
    const int ga = (NA_N + 63) / 64;
    const int ab4 = (NA_N + 3) / 4;
    const int bb4 = (NB_N + 3) / 4;

    // ---- layer 0 (D = 128): h written as bf16 only ----
    agg_mean_bf<DIN_N><<<bb4, 256, 0, stream>>>(xa_bf, ssrc_ab, off_b, agg1, NB_N);
    mfma_gemm_norm_lrelu<DIN_N, true><<<gb, 256, 0, stream>>>(
        agg1, xb_bf, wt_l0ab, wt_r0ab, b0_ab, nullptr, hb_bf, NB_N);
    agg_mean_bf<DIN_N><<<ab4, 256, 0, stream>>>(xb_bf, ssrc_ba, off_a, agg2, NA_N);
    mfma_gemm_norm_lrelu<DIN_N, true><<<ga, 256, 0, stream>>>(
        agg2, xa_bf, wt_l0ba, wt_r0ba, b0_ba, nullptr, ha_bf, NA_N);

    // ---- layer 1 (D = 256): fp32 final outputs ----
    agg_mean_bf<HID_N><<<bb4, 256, 0, stream>>>(ha_bf, ssrc_ab, off_b, agg1, NB_N);
    agg_mean_bf<HID_N><<<ab4, 256, 0, stream>>>(hb_bf, ssrc_ba, off_a, agg2, NA_N);
    mfma_gemm_norm_lrelu<HID_N, false><<<gb, 256, 0, stream>>>(
        agg1, hb_bf, wt_l1ab, wt_r1ab, b1_ab, out_b, nullptr, NB_N);
    mfma_gemm_norm_lrelu<HID_N, false><<<ga, 256, 0, stream>>>(
        agg2, ha_bf, wt_l1ba, wt_r1ba, b1_ba, out_a, nullptr, NA_N);
}

// Round 6
// 411.431 us; speedup vs baseline: 3.6934x; 1.1505x over previous
//
#include <hip/hip_runtime.h>
#include <hip/hip_bf16.h>
#include <math.h>
#include <string.h>

#define NA_N 50000
#define NB_N 50000
#define DIN_N 128
#define HID_N 256
#define NE_N 1000000

#define BSHIFT 9
#define BSIZE (1 << BSHIFT)
#define NBUCK ((NA_N + BSIZE - 1) >> BSHIFT)       // 98
#define CHUNK 4096

typedef short short8 __attribute__((ext_vector_type(8)));
typedef float f32x4 __attribute__((ext_vector_type(4)));
typedef unsigned int uint4v __attribute__((ext_vector_type(4)));

#define GLDS16(gp, lp) __builtin_amdgcn_global_load_lds( \
    (const __attribute__((address_space(1))) void*)(gp), \
    (__attribute__((address_space(3))) void*)(lp), 16, 0, 0)

static __device__ __forceinline__ float lrelu(float x) {
    return x >= 0.0f ? x : 0.01f * x;
}

static __device__ __forceinline__ unsigned short f2bf(float f) {
    __hip_bfloat16 h = __float2bfloat16(f);   // RNE
    unsigned short u;
    memcpy(&u, &h, 2);
    return u;
}

static __device__ __forceinline__ float bf2f(unsigned short u) {
    unsigned int x = ((unsigned int)u) << 16;
    float f;
    memcpy(&f, &x, 4);
    return f;
}

// chunk swizzle for 64B LDS rows of 4x16B chunks
static __device__ __forceinline__ int swz(int r) { return (r & 3) ^ ((r >> 2) & 3); }

// ---------------- fp32 -> bf16 convert (two arrays in one launch) ----------------

__global__ void f2bf_arr2(const float* __restrict__ inA, unsigned short* __restrict__ outA,
                          const float* __restrict__ inB, unsigned short* __restrict__ outB, int n4) {
    int i = blockIdx.x * blockDim.x + threadIdx.x;
    const float* in = blockIdx.y ? inB : inA;
    unsigned short* out = blockIdx.y ? outB : outA;
    if (i < n4) {
        float4 v = ((const float4*)in)[i];
        ushort4 b;
        b.x = f2bf(v.x); b.y = f2bf(v.y); b.z = f2bf(v.z); b.w = f2bf(v.w);
        ((ushort4*)out)[i] = b;
    }
}

// ---------------- weight transposes: 8 in one launch ----------------

struct TW { const float* W; unsigned short* T; int D; };
struct TW8 { TW t[8]; };

__global__ void transpose_w8(TW8 a) {
    TW t = a.t[blockIdx.y];
    int wg = blockIdx.x * 4 + (threadIdx.x >> 6);
    int lane = threadIdx.x & 63;
    int kchunks = t.D >> 6;
    int c = wg / kchunks;
    int kc = wg - c * kchunks;
    int k = kc * 64 + lane;
    if (c < 256) t.T[(size_t)c * t.D + k] = f2bf(t.W[(size_t)k * 256 + c]);
}

// ---------------- bucketed CSR build (merged over both edge types) ----------------

__global__ __launch_bounds__(256)
void coarse_hist2(const int* __restrict__ dstA, const int* __restrict__ dstB, int E,
                  int* __restrict__ ghA, int* __restrict__ ghB) {
    const int* dst = blockIdx.y ? dstB : dstA;
    int* ghist = blockIdx.y ? ghB : ghA;
    __shared__ int lc[NBUCK];
    for (int i = threadIdx.x; i < NBUCK; i += 256) lc[i] = 0;
    __syncthreads();
    int base = blockIdx.x * CHUNK;
    int end = min(base + CHUNK, E);
    for (int i = base + threadIdx.x; i < end; i += 256)
        atomicAdd(&lc[dst[i] >> BSHIFT], 1);
    __syncthreads();
    for (int i = threadIdx.x; i < NBUCK; i += 256)
        if (lc[i]) atomicAdd(&ghist[i], lc[i]);
}

__global__ void bucket_scan2(const int* __restrict__ ghA, int* __restrict__ cbA, int* __restrict__ curA,
                             const int* __restrict__ ghB, int* __restrict__ cbB, int* __restrict__ curB) {
    const int* ghist = blockIdx.x ? ghB : ghA;
    int* cbase = blockIdx.x ? cbB : cbA;
    int* cursor = blockIdx.x ? curB : curA;
    int tid = threadIdx.x;
    int v = (tid < NBUCK) ? ghist[tid] : 0;
    int incl = v;
    #pragma unroll
    for (int m = 1; m < 64; m <<= 1) {
        int o = __shfl_up(incl, m, 64);
        if ((tid & 63) >= m) incl += o;
    }
    __shared__ int wsum[2];
    if ((tid & 63) == 63) wsum[tid >> 6] = incl;
    __syncthreads();
    if (tid >= 64) incl += wsum[0];
    if (tid < NBUCK) {
        cbase[tid] = incl - v;
        cursor[tid] = incl - v;
    }
    if (tid == 127) cbase[NBUCK] = incl;
}

__global__ __launch_bounds__(256)
void coarse_scatter2(const int* __restrict__ eiA, const int* __restrict__ eiB, int E,
                     int* __restrict__ curA, unsigned long long* __restrict__ bkA,
                     int* __restrict__ curB, unsigned long long* __restrict__ bkB) {
    const int* src = blockIdx.y ? eiB : eiA;
    const int* dst = src + E;
    int* cursor = blockIdx.y ? curB : curA;
    unsigned long long* bucketed = blockIdx.y ? bkB : bkA;
    __shared__ int lc[NBUCK];
    __shared__ int gb[NBUCK];
    for (int i = threadIdx.x; i < NBUCK; i += 256) lc[i] = 0;
    __syncthreads();
    int base = blockIdx.x * CHUNK;
    int end = min(base + CHUNK, E);
    for (int i = base + threadIdx.x; i < end; i += 256)
        atomicAdd(&lc[dst[i] >> BSHIFT], 1);
    __syncthreads();
    for (int i = threadIdx.x; i < NBUCK; i += 256) {
        int c = lc[i];
        gb[i] = c ? atomicAdd(&cursor[i], c) : 0;
        lc[i] = 0;
    }
    __syncthreads();
    for (int i = base + threadIdx.x; i < end; i += 256) {
        int d = dst[i];
        int bk = d >> BSHIFT;
        int p = atomicAdd(&lc[bk], 1);
        bucketed[(size_t)gb[bk] + p] = ((unsigned long long)(unsigned int)d << 32) |
                                       (unsigned int)src[i];
    }
}

__global__ __launch_bounds__(256)
void fine_scatter2(const unsigned long long* __restrict__ bkA, const int* __restrict__ cbA,
                   int* __restrict__ offsA, int* __restrict__ ssrcA,
                   const unsigned long long* __restrict__ bkB, const int* __restrict__ cbB,
                   int* __restrict__ offsB, int* __restrict__ ssrcB, int n, int E) {
    const unsigned long long* bucketed = blockIdx.y ? bkB : bkA;
    const int* cbase = blockIdx.y ? cbB : cbA;
    int* offs = blockIdx.y ? offsB : offsA;
    int* ssrc = blockIdx.y ? ssrcB : ssrcA;
    int bk = blockIdx.x;
    int ebeg = cbase[bk], eend = cbase[bk + 1];
    int d0 = bk << BSHIFT;
    __shared__ int dc[BSIZE];
    __shared__ int wp[4];
    int tid = threadIdx.x;
    for (int i = tid; i < BSIZE; i += 256) dc[i] = 0;
    __syncthreads();
    for (int i = ebeg + tid; i < eend; i += 256) {
        int dl = (int)(bucketed[i] >> 32) - d0;
        atomicAdd(&dc[dl], 1);
    }
    __syncthreads();
    int a = dc[2 * tid], b = dc[2 * tid + 1];
    int s = a + b;
    int incl = s;
    #pragma unroll
    for (int m = 1; m < 64; m <<= 1) {
        int o = __shfl_up(incl, m, 64);
        if ((tid & 63) >= m) incl += o;
    }
    if ((tid & 63) == 63) wp[tid >> 6] = incl;
    __syncthreads();
    int add = 0;
    for (int w0 = 0; w0 < (tid >> 6); ++w0) add += wp[w0];
    incl += add;
    int excl = incl - s;
    dc[2 * tid] = excl;
    dc[2 * tid + 1] = excl + a;
    int d = d0 + 2 * tid;
    if (d < n) offs[d] = ebeg + excl;
    if (d + 1 < n) offs[d + 1] = ebeg + excl + a;
    if (bk == (int)gridDim.x - 1 && tid == 0) offs[n] = E;
    __syncthreads();
    for (int i = ebeg + tid; i < eend; i += 256) {
        unsigned long long e = bucketed[i];
        int dl = (int)(e >> 32) - d0;
        int p = atomicAdd(&dc[dl], 1);
        ssrc[ebeg + p] = (int)(e & 0xffffffffu);
    }
}

// -------- aggregation: one wave per destination, edge-parallel lane groups --------

struct AggP {
    const unsigned short* xsrc;
    const int* ssrc;
    const int* offs;
    unsigned short* mean;
};

template <int D>
__global__ __launch_bounds__(256)
void agg_mean2(AggP p0, AggP p1, int n) {
    AggP P = blockIdx.y ? p1 : p0;
    constexpr int G = D / 8;
    constexpr int EPW = 64 / G;
    constexpr int U = (D == 256) ? 4 : 3;
    int w = blockIdx.x * 4 + (threadIdx.x >> 6);
    if (w >= n) return;
    const int lane = threadIdx.x & 63;
    const int grp = lane / G;
    const int pos = lane % G;
    const int beg = P.offs[w], end = P.offs[w + 1];

    float acc[8];
    #pragma unroll
    for (int c = 0; c < 8; ++c) acc[c] = 0.0f;

    const unsigned short* base = P.xsrc + pos * 8;
    for (int e = beg; e < end; e += EPW * U) {
        int idx[U];
        float wt[U];
        #pragma unroll
        for (int u = 0; u < U; ++u) {
            int ee = e + u * EPW + grp;
            idx[u] = P.ssrc[ee < end ? ee : end - 1];
            wt[u] = (ee < end) ? 1.0f : 0.0f;
        }
        uint4v v[U];
        #pragma unroll
        for (int u = 0; u < U; ++u)
            v[u] = *(const uint4v*)(base + (size_t)idx[u] * D);
        #pragma unroll
        for (int u = 0; u < U; ++u)
            #pragma unroll
            for (int c = 0; c < 4; ++c) {
                unsigned int q = v[u][c];
                acc[2 * c]     = fmaf(wt[u], __uint_as_float(q << 16), acc[2 * c]);
                acc[2 * c + 1] = fmaf(wt[u], __uint_as_float(q & 0xffff0000u), acc[2 * c + 1]);
            }
    }
    #pragma unroll
    for (int m = G; m < 64; m <<= 1)
        #pragma unroll
        for (int c = 0; c < 8; ++c)
            acc[c] += __shfl_xor(acc[c], m, 64);
    if (lane < G) {
        float inv = 1.0f / fmaxf((float)(end - beg), 1.0f);
        uint4v o;
        #pragma unroll
        for (int c = 0; c < 4; ++c)
            o[c] = ((unsigned int)f2bf(acc[2 * c + 1] * inv) << 16) | f2bf(acc[2 * c] * inv);
        *(uint4v*)(P.mean + (size_t)w * D + pos * 8) = o;
    }
}

// ------- fused MFMA dual-GEMM + bias + L2-normalize + leaky_relu (v2) -------
// BM=128, BN=256, BK=32, 512 threads (8 waves: 2 row-groups x 4 col-groups).
// global_load_lds staging; linear 64B LDS rows; chunk-XOR swizzle on both sides.

struct GP {
    const unsigned short* A;
    const unsigned short* X;
    const unsigned short* Wtl;
    const unsigned short* Wtr;
    const float* bias;
    float* outf;
    unsigned short* outb;
};

template <int D, bool BF16OUT>
__global__ __launch_bounds__(512)
void mfma_gemm2(GP p0, GP p1, int n) {
    GP P = blockIdx.y ? p1 : p0;
    constexpr int BM = 128, BK = 32;
    __shared__ __align__(16) unsigned short Asl[BM * BK];     //  8 KB
    __shared__ __align__(16) unsigned short Wsl[256 * BK];    // 16 KB
    __shared__ float red[4][BM];
    __shared__ float invn[BM];

    const int tid = threadIdx.x;
    const int wid = tid >> 6;
    const int lane = tid & 63;
    const int wr = wid >> 2, wc = wid & 3;
    const int cl = lane & 15, g = lane >> 4;
    const int row0 = blockIdx.x * BM;
    const bool full = (row0 + BM <= n);

    f32x4 acc[4][4];
    #pragma unroll
    for (int m = 0; m < 4; ++m)
        #pragma unroll
        for (int nn = 0; nn < 4; ++nn)
            acc[m][nn] = (f32x4){0.f, 0.f, 0.f, 0.f};

    #pragma unroll
    for (int pass = 0; pass < 2; ++pass) {
        const unsigned short* __restrict__ M = pass ? P.X : P.A;
        const unsigned short* __restrict__ Wt = pass ? P.Wtr : P.Wtl;
        for (int k0 = 0; k0 < D; k0 += BK) {
            __syncthreads();
            // stage A tile (128 x 32 bf16 = 8KB): one 16B glds per thread
            if (full) {
                int r = wid * 16 + (lane >> 2);
                int c = lane & 3;
                const unsigned short* src = M + (size_t)(row0 + r) * D + k0 + ((c ^ swz(r)) << 3);
                GLDS16(src, &Asl[wid * 512]);
            } else {
                int r = tid >> 2, c = tid & 3;
                short8 v = {0, 0, 0, 0, 0, 0, 0, 0};
                if (row0 + r < n)
                    v = *(const short8*)(M + (size_t)(row0 + r) * D + k0 + ((c ^ swz(r)) << 3));
                *(short8*)(&Asl[r * 32 + (c << 3)]) = v;
            }
            // stage W tile (256 x 32 bf16 = 16KB): two 16B glds per thread
            #pragma unroll
            for (int q = 0; q < 2; ++q) {
                int rw = q * 128 + wid * 16 + (lane >> 2);
                int c = lane & 3;
                const unsigned short* src = Wt + (size_t)rw * D + k0 + ((c ^ swz(rw)) << 3);
                GLDS16(src, &Wsl[(q * 128 + wid * 16) * 32]);
            }
            __syncthreads();
            short8 af[4], bfr[4];
            #pragma unroll
            for (int m = 0; m < 4; ++m) {
                int R = wr * 64 + m * 16 + cl;
                af[m] = *(const short8*)(&Asl[R * 32 + ((g ^ swz(R)) << 3)]);
            }
            #pragma unroll
            for (int nn = 0; nn < 4; ++nn) {
                int C = wc * 64 + nn * 16 + cl;
                bfr[nn] = *(const short8*)(&Wsl[C * 32 + ((g ^ swz(C)) << 3)]);
            }
            #pragma unroll
            for (int m = 0; m < 4; ++m)
                #pragma unroll
                for (int nn = 0; nn < 4; ++nn)
                    acc[m][nn] = __builtin_amdgcn_mfma_f32_16x16x32_bf16(
                        af[m], bfr[nn], acc[m][nn], 0, 0, 0);
        }
    }

    // ---- epilogue: bias, row L2-norm, leaky-relu ----
    float bv[4];
    #pragma unroll
    for (int nn = 0; nn < 4; ++nn) bv[nn] = P.bias[wc * 64 + nn * 16 + cl];

    float ss[4][4];
    #pragma unroll
    for (int m = 0; m < 4; ++m)
        #pragma unroll
        for (int r = 0; r < 4; ++r) {
            float s = 0.f;
            #pragma unroll
            for (int nn = 0; nn < 4; ++nn) {
                acc[m][nn][r] += bv[nn];
                s = fmaf(acc[m][nn][r], acc[m][nn][r], s);
            }
            ss[m][r] = s;
        }
    #pragma unroll
    for (int mask = 1; mask < 16; mask <<= 1)
        #pragma unroll
        for (int m = 0; m < 4; ++m)
            #pragma unroll
            for (int r = 0; r < 4; ++r)
                ss[m][r] += __shfl_xor(ss[m][r], mask, 64);
    if (cl == 0) {
        #pragma unroll
        for (int m = 0; m < 4; ++m)
            #pragma unroll
            for (int r = 0; r < 4; ++r)
                red[wc][wr * 64 + m * 16 + g * 4 + r] = ss[m][r];
    }
    __syncthreads();
    if (tid < BM) {
        float tot = red[0][tid] + red[1][tid] + red[2][tid] + red[3][tid];
        invn[tid] = 1.0f / fmaxf(sqrtf(tot), 1e-12f);
    }
    __syncthreads();
    #pragma unroll
    for (int m = 0; m < 4; ++m)
        #pragma unroll
        for (int r = 0; r < 4; ++r) {
            int row = wr * 64 + m * 16 + g * 4 + r;
            if (row0 + row < n) {
                float iv = invn[row];
                #pragma unroll
                for (int nn = 0; nn < 4; ++nn) {
                    float o = lrelu(acc[m][nn][r] * iv);
                    size_t off = (size_t)(row0 + row) * HID_N + wc * 64 + nn * 16 + cl;
                    if constexpr (BF16OUT) P.outb[off] = f2bf(o);
                    else P.outf[off] = o;
                }
            }
        }
}

// ---------------- launcher ----------------

extern "C" void kernel_launch(void* const* d_in, const int* in_sizes, int n_in,
                              void* d_out, int out_size, void* d_ws, size_t ws_size,
                              hipStream_t stream) {
    const float* xa = (const float*)d_in[0];
    const float* xb = (const float*)d_in[1];
    const int* ei_ab = (const int*)d_in[2];
    const int* ei_ba = (const int*)d_in[3];
    const float* Wl0_ab = (const float*)d_in[4];
    const float* Wr0_ab = (const float*)d_in[5];
    const float* b0_ab = (const float*)d_in[6];
    const float* Wl0_ba = (const float*)d_in[7];
    const float* Wr0_ba = (const float*)d_in[8];
    const float* b0_ba = (const float*)d_in[9];
    const float* Wl1_ab = (const float*)d_in[10];
    const float* Wr1_ab = (const float*)d_in[11];
    const float* b1_ab = (const float*)d_in[12];
    const float* Wl1_ba = (const float*)d_in[13];
    const float* Wr1_ba = (const float*)d_in[14];
    const float* b1_ba = (const float*)d_in[15];

    float* out_a = (float*)d_out;
    float* out_b = out_a + (size_t)NA_N * HID_N;

    char* w = (char*)d_ws;
    auto carve = [&](size_t bytes) -> char* {
        char* p = w;
        w += (bytes + 255) & ~(size_t)255;
        return p;
    };
    unsigned short* agg1 = (unsigned short*)carve((size_t)NB_N * HID_N * 2);
    unsigned short* agg2 = (unsigned short*)carve((size_t)NA_N * HID_N * 2);
    unsigned long long* bucketed_b = (unsigned long long*)agg1;   // aliases agg1 (dead before aggs)
    unsigned long long* bucketed_a = (unsigned long long*)agg2;
    unsigned short* xa_bf = (unsigned short*)carve((size_t)NA_N * DIN_N * 2);
    unsigned short* xb_bf = (unsigned short*)carve((size_t)NB_N * DIN_N * 2);
    unsigned short* ha_bf = (unsigned short*)carve((size_t)NA_N * HID_N * 2);
    unsigned short* hb_bf = (unsigned short*)carve((size_t)NB_N * HID_N * 2);
    int* off_b = (int*)carve((size_t)(NB_N + 1) * 4);
    int* off_a = (int*)carve((size_t)(NA_N + 1) * 4);
    int* ghist_b = (int*)carve(2 * NBUCK * 4);     // ghist_b and ghist_a contiguous
    int* ghist_a = ghist_b + NBUCK;
    int* cbase_b = (int*)carve((NBUCK + 1) * 4);
    int* cbase_a = (int*)carve((NBUCK + 1) * 4);
    int* cursor_b = (int*)carve(NBUCK * 4);
    int* cursor_a = (int*)carve(NBUCK * 4);
    int* ssrc_ab = (int*)carve((size_t)NE_N * 4);
    int* ssrc_ba = (int*)carve((size_t)NE_N * 4);
    unsigned short* wt_l0ab = (unsigned short*)carve((size_t)DIN_N * 256 * 2);
    unsigned short* wt_r0ab = (unsigned short*)carve((size_t)DIN_N * 256 * 2);
    unsigned short* wt_l0ba = (unsigned short*)carve((size_t)DIN_N * 256 * 2);
    unsigned short* wt_r0ba = (unsigned short*)carve((size_t)DIN_N * 256 * 2);
    unsigned short* wt_l1ab = (unsigned short*)carve((size_t)HID_N * 256 * 2);
    unsigned short* wt_r1ab = (unsigned short*)carve((size_t)HID_N * 256 * 2);
    unsigned short* wt_l1ba = (unsigned short*)carve((size_t)HID_N * 256 * 2);
    unsigned short* wt_r1ba = (unsigned short*)carve((size_t)HID_N * 256 * 2);

    hipMemsetAsync(ghist_b, 0, 2 * NBUCK * 4, stream);

    {
        dim3 g((NA_N * DIN_N / 4 + 255) / 256, 2);
        f2bf_arr2<<<g, 256, 0, stream>>>(xa, xa_bf, xb, xb_bf, NA_N * DIN_N / 4);
    }
    {
        TW8 a;
        a.t[0] = {Wl0_ab, wt_l0ab, DIN_N}; a.t[1] = {Wr0_ab, wt_r0ab, DIN_N};
        a.t[2] = {Wl0_ba, wt_l0ba, DIN_N}; a.t[3] = {Wr0_ba, wt_r0ba, DIN_N};
        a.t[4] = {Wl1_ab, wt_l1ab, HID_N}; a.t[5] = {Wr1_ab, wt_r1ab, HID_N};
        a.t[6] = {Wl1_ba, wt_l1ba, HID_N}; a.t[7] = {Wr1_ba, wt_r1ba, HID_N};
        dim3 g(256, 8);
        transpose_w8<<<g, 256, 0, stream>>>(a);
    }

    const int cgrid = (NE_N + CHUNK - 1) / CHUNK;
    {
        dim3 g(cgrid, 2);
        coarse_hist2<<<g, 256, 0, stream>>>(ei_ab + NE_N, ei_ba + NE_N, NE_N, ghist_b, ghist_a);
    }
    bucket_scan2<<<2, 128, 0, stream>>>(ghist_b, cbase_b, cursor_b, ghist_a, cbase_a, cursor_a);
    {
        dim3 g(cgrid, 2);
        coarse_scatter2<<<g, 256, 0, stream>>>(ei_ab, ei_ba, NE_N,
                                               cursor_b, bucketed_b, cursor_a, bucketed_a);
    }
    {
        dim3 g(NBUCK, 2);
        fine_scatter2<<<g, 256, 0, stream>>>(bucketed_b, cbase_b, off_b, ssrc_ab,
                                             bucketed_a, cbase_a, off_a, ssrc_ba, NA_N, NE_N);
    }

    const dim3 gagg((NA_N + 3) / 4, 2);
    const dim3 ggemm((NA_N + 127) / 128, 2);

    // ---- layer 0 (D = 128): h written as bf16 ----
    agg_mean2<DIN_N><<<gagg, 256, 0, stream>>>(
        AggP{xa_bf, ssrc_ab, off_b, agg1}, AggP{xb_bf, ssrc_ba, off_a, agg2}, NA_N);
    mfma_gemm2<DIN_N, true><<<ggemm, 512, 0, stream>>>(
        GP{agg1, xb_bf, wt_l0ab, wt_r0ab, b0_ab, nullptr, hb_bf},
        GP{agg2, xa_bf, wt_l0ba, wt_r0ba, b0_ba, nullptr, ha_bf}, NA_N);

    // ---- layer 1 (D = 256): fp32 final outputs ----
    agg_mean2<HID_N><<<gagg, 256, 0, stream>>>(
        AggP{ha_bf, ssrc_ab, off_b, agg1}, AggP{hb_bf, ssrc_ba, off_a, agg2}, NA_N);
    mfma_gemm2<HID_N, false><<<ggemm, 512, 0, stream>>>(
        GP{agg1, hb_bf, wt_l1ab, wt_r1ab, b1_ab, out_b, nullptr},
        GP{agg2, ha_bf, wt_l1ba, wt_r1ba, b1_ba, out_a, nullptr}, NA_N);
}